// Round 9
// baseline (494.558 us; speedup 1.0000x reference)
//
#include <hip/hip_runtime.h>
#include <hip/hip_bf16.h>
#include <cstdint>
#include <cstddef>

typedef __bf16 bf16;
typedef __attribute__((ext_vector_type(8))) __bf16 bf16x8;
typedef __attribute__((ext_vector_type(4))) float f32x4;

#define BB 4
#define TT 4096
#define DD 512
#define MM (BB * TT)              // 16384 rows
#define OUT1_OFF ((size_t)MM * DD)

typedef __attribute__((address_space(1))) void as1_void;
typedef __attribute__((address_space(3))) void as3_void;

__device__ __forceinline__ void gl_lds16(const void* g, void* l) {
    __builtin_amdgcn_global_load_lds((as1_void*)(uintptr_t)g,
                                     (as3_void*)(uintptr_t)l, 16, 0, 0);
}

// ---------------------------------------------------------------- transpose
__global__ void transpose_bf16(const float* __restrict__ in, bf16* __restrict__ out,
                               int R, int C) {
    __shared__ float tile[32][33];
    const int c0 = blockIdx.x * 32, r0 = blockIdx.y * 32;
    const int tx = threadIdx.x, ty = threadIdx.y;
#pragma unroll
    for (int i = 0; i < 32; i += 8)
        tile[ty + i][tx] = in[(size_t)(r0 + ty + i) * C + (c0 + tx)];
    __syncthreads();
#pragma unroll
    for (int i = 0; i < 32; i += 8)
        out[(size_t)(c0 + ty + i) * R + (r0 + tx)] = (bf16)tile[tx][ty + i];
}

__global__ void pack_bias(const float* __restrict__ a, const float* __restrict__ b,
                          const float* __restrict__ c, const float* __restrict__ d,
                          float* __restrict__ o) {
    const int i = blockIdx.x * 256 + threadIdx.x;
    if (i < 2048) {
        const float* s = (i < 512) ? a : (i < 1024) ? b : (i < 1536) ? c : d;
        o[i] = s[i & 511];
    }
}

__global__ void zero_kernel(float* __restrict__ p, int n) {
    const int i = blockIdx.x * 256 + threadIdx.x;
    if (i < n) p[i] = 0.f;
}

// ---------------------------------------------------------------- layernorm
__global__ __launch_bounds__(256) void ln_kernel(
    const float* __restrict__ X, const float* __restrict__ Xadd,
    const float* __restrict__ gw, const float* __restrict__ bw,
    bf16* __restrict__ out) {
    const int row = blockIdx.x * 4 + (threadIdx.x >> 6);
    const int lane = threadIdx.x & 63;
    const float* xr = X + (size_t)row * DD + lane * 8;
    float v[8];
    float4 v0 = *(const float4*)xr;
    float4 v1 = *(const float4*)(xr + 4);
    v[0] = v0.x; v[1] = v0.y; v[2] = v0.z; v[3] = v0.w;
    v[4] = v1.x; v[5] = v1.y; v[6] = v1.z; v[7] = v1.w;
    if (Xadd) {
        const float* ad = Xadd + (size_t)row * DD + lane * 8;
        float4 a0 = *(const float4*)ad;
        float4 a1 = *(const float4*)(ad + 4);
        v[0] += a0.x; v[1] += a0.y; v[2] += a0.z; v[3] += a0.w;
        v[4] += a1.x; v[5] += a1.y; v[6] += a1.z; v[7] += a1.w;
    }
    float s = 0.f, ss = 0.f;
#pragma unroll
    for (int i = 0; i < 8; ++i) { s += v[i]; ss += v[i] * v[i]; }
#pragma unroll
    for (int o = 32; o; o >>= 1) { s += __shfl_down(s, o); ss += __shfl_down(ss, o); }
    s = __shfl(s, 0); ss = __shfl(ss, 0);
    const float mu = s * (1.f / DD);
    const float var = ss * (1.f / DD) - mu * mu;
    const float rstd = rsqrtf(var + 1e-5f);
    bf16x8 o8;
#pragma unroll
    for (int i = 0; i < 8; ++i)
        o8[i] = (bf16)((v[i] - mu) * rstd * gw[lane * 8 + i] + bw[lane * 8 + i]);
    *(bf16x8*)(out + (size_t)row * DD + lane * 8) = o8;
}

#define MF(a_, b_, c_) c_ = __builtin_amdgcn_mfma_f32_16x16x32_bf16(a_, b_, c_, 0, 0, 0)

// ---------------------------------------------------------------- GEMM 256x256 8-wave 4-phase
// BM=BN=256, BK=64, 8 waves (2M x 4N), per-wave C = 128x64 (acc[8][4]).
// LDS 128KB: [2 buf][A,B][2 half][128 rows][64 cols] bf16, rows 128B.
// Read swizzle: 16B slot s_phys = s_log ^ (row&7)  (kills the stride-128B
// 16-way conflict). Applied via pre-swizzled GLOBAL source on staging
// (linear gl_lds dest) + swizzled ds_read (rule 21 both-sides involution).
// Per K-tile: 4 phases {12 ds_read -> stage 1 half of kt+1 (2 gl_lds) ->
// s_barrier -> setprio(1) 16 MFMA setprio(0) -> s_barrier}; one
// __syncthreads per tile (guards dbuf reuse + prefetch landing).
// MODE 0: f32 cols<512 -> Cout (linp); bf16 cols>=512 -> Cout2 (lint)
// MODE 1: bf16 out = gelu(acc + bias)
template <int MODE>
__global__ __launch_bounds__(512, 2) void gemm8p(
    const bf16* __restrict__ A, const bf16* __restrict__ Bt,
    const float* __restrict__ bias, void* __restrict__ Cout,
    void* __restrict__ Cout2, int M, int N, int K) {
    __shared__ bf16 lds[2][2][2][128 * 64];
    const int tid = threadIdx.x, lane = tid & 63, wv = tid >> 6;
    const int wr = wv >> 2, wc = wv & 3;
    const int lr = lane & 15, lg = lane >> 4;
    const int nb = N >> 8;
    const int nwg = gridDim.x;
    int bx = blockIdx.x;
    if ((nwg & 7) == 0) bx = (bx & 7) * (nwg >> 3) + (bx >> 3);
    const int bm = bx / nb, bn = bx % nb;
    const int m0 = bm << 8, n0 = bn << 8;

    // staging thread map: row (within half) = (t>>3) + j*64, 16B slot = t&7
    const int srow = tid >> 3;
    const int scol = (((tid & 7) ^ (srow & 7)) << 3);   // pre-swizzled global col
    const bf16* Asrc = A + (size_t)(m0 + srow) * K + scol;
    const bf16* Bsrc = Bt + (size_t)(n0 + srow) * K + scol;
    const size_t r64 = (size_t)64 * K;
    const size_t r128 = (size_t)128 * K;

#define STAGE_H(bufi, mat, half, kt)                                              \
    do {                                                                          \
        const bf16* s_ = ((mat) == 0 ? Asrc : Bsrc) + (half) * r128 + (kt) * 64;  \
        bf16* d_ = &lds[bufi][mat][half][wv * 512];                               \
        gl_lds16(s_, d_);                                                         \
        gl_lds16(s_ + r64, d_ + 4096);                                            \
    } while (0)

    const int psel0 = ((lg ^ (lr & 7)) << 3);          // ks=0 slot (swizzled)
    const int psel1 = (((4 + lg) ^ (lr & 7)) << 3);    // ks=1 slot

    f32x4 acc[8][4] = {};

#define PHASE(bufi, qm, qn, kt1, smat, shalf, dostage)                             \
    do {                                                                           \
        const bf16* Ah_ = &lds[bufi][0][wr][0];                                    \
        const bf16* Bh_ = &lds[bufi][1][wc >> 1][0];                               \
        const int rA_ = ((qm) * 64 + lr) * 64;                                     \
        const int rB_ = ((wc & 1) * 64 + (qn) * 32 + lr) * 64;                     \
        bf16x8 a0_ = *(const bf16x8*)&Ah_[rA_ + psel0];                            \
        bf16x8 a1_ = *(const bf16x8*)&Ah_[rA_ + 1024 + psel0];                     \
        bf16x8 a2_ = *(const bf16x8*)&Ah_[rA_ + 2048 + psel0];                     \
        bf16x8 a3_ = *(const bf16x8*)&Ah_[rA_ + 3072 + psel0];                     \
        bf16x8 b0_ = *(const bf16x8*)&Bh_[rB_ + psel0];                            \
        bf16x8 b1_ = *(const bf16x8*)&Bh_[rB_ + 1024 + psel0];                     \
        bf16x8 a0b_ = *(const bf16x8*)&Ah_[rA_ + psel1];                           \
        bf16x8 a1b_ = *(const bf16x8*)&Ah_[rA_ + 1024 + psel1];                    \
        bf16x8 a2b_ = *(const bf16x8*)&Ah_[rA_ + 2048 + psel1];                    \
        bf16x8 a3b_ = *(const bf16x8*)&Ah_[rA_ + 3072 + psel1];                    \
        bf16x8 b0b_ = *(const bf16x8*)&Bh_[rB_ + psel1];                           \
        bf16x8 b1b_ = *(const bf16x8*)&Bh_[rB_ + 1024 + psel1];                    \
        if (dostage) STAGE_H((bufi) ^ 1, smat, shalf, kt1);                        \
        __builtin_amdgcn_s_barrier();                                              \
        __builtin_amdgcn_s_setprio(1);                                            \
        MF(a0_, b0_, acc[(qm)*4+0][(qn)*2+0]);                                     \
        MF(a1_, b0_, acc[(qm)*4+1][(qn)*2+0]);                                     \
        MF(a2_, b0_, acc[(qm)*4+2][(qn)*2+0]);                                     \
        MF(a3_, b0_, acc[(qm)*4+3][(qn)*2+0]);                                     \
        MF(a0_, b1_, acc[(qm)*4+0][(qn)*2+1]);                                     \
        MF(a1_, b1_, acc[(qm)*4+1][(qn)*2+1]);                                     \
        MF(a2_, b1_, acc[(qm)*4+2][(qn)*2+1]);                                     \
        MF(a3_, b1_, acc[(qm)*4+3][(qn)*2+1]);                                     \
        MF(a0b_, b0b_, acc[(qm)*4+0][(qn)*2+0]);                                   \
        MF(a1b_, b0b_, acc[(qm)*4+1][(qn)*2+0]);                                   \
        MF(a2b_, b0b_, acc[(qm)*4+2][(qn)*2+0]);                                   \
        MF(a3b_, b0b_, acc[(qm)*4+3][(qn)*2+0]);                                   \
        MF(a0b_, b1b_, acc[(qm)*4+0][(qn)*2+1]);                                   \
        MF(a1b_, b1b_, acc[(qm)*4+1][(qn)*2+1]);                                   \
        MF(a2b_, b1b_, acc[(qm)*4+2][(qn)*2+1]);                                   \
        MF(a3b_, b1b_, acc[(qm)*4+3][(qn)*2+1]);                                   \
        __builtin_amdgcn_s_setprio(0);                                             \
        __builtin_amdgcn_s_barrier();                                              \
    } while (0)

    const int NKT = K >> 6;
    STAGE_H(0, 0, 0, 0); STAGE_H(0, 0, 1, 0);
    STAGE_H(0, 1, 0, 0); STAGE_H(0, 1, 1, 0);
    __syncthreads();
    for (int kt = 0; kt < NKT; ++kt) {
        const int buf = kt & 1;
        const bool st = (kt + 1 < NKT);
        PHASE(buf, 0, 0, kt + 1, 0, 0, st);
        PHASE(buf, 1, 0, kt + 1, 0, 1, st);
        PHASE(buf, 0, 1, kt + 1, 1, 0, st);
        PHASE(buf, 1, 1, kt + 1, 1, 1, st);
        __syncthreads();
    }
#undef PHASE
#undef STAGE_H

#pragma unroll
    for (int mi = 0; mi < 8; ++mi) {
#pragma unroll
        for (int ni = 0; ni < 4; ++ni) {
            const int gmb = m0 + wr * 128 + mi * 16 + 4 * lg;
            const int gn = n0 + wc * 64 + ni * 16 + lr;
            const float bia = bias[gn];
#pragma unroll
            for (int i = 0; i < 4; ++i) {
                float v = acc[mi][ni][i] + bia;
                const int row = gmb + i;
                if (MODE == 0) {
                    if (gn < 512) ((float*)Cout)[(size_t)row * 512 + gn] = v;
                    else ((bf16*)Cout2)[(size_t)row * 1536 + (gn - 512)] = (bf16)v;
                } else {
                    const float ge = 0.5f * v * (1.0f + erff(v * 0.70710678118654752f));
                    ((bf16*)Cout)[(size_t)row * N + gn] = (bf16)ge;
                }
            }
        }
    }
}

// ---------------------------------------------------------------- GEMM 128x128 (R6, for FFN2)
template <int MODE>
__global__ __launch_bounds__(256) void gemm_bt(
    const bf16* __restrict__ A, const bf16* __restrict__ Bt,
    const float* __restrict__ bias, void* __restrict__ Cout,
    void* __restrict__ Cout2,
    const float* __restrict__ add1, const float* __restrict__ add2,
    int M, int N, int K) {
    __shared__ bf16 As[2][4096];
    __shared__ bf16 Bs[2][4096];
    const int tid = threadIdx.x;
    const int lane = tid & 63;
    const int wv = tid >> 6;
    const int wr = wv >> 1, wc = wv & 1;
    const int nb = N >> 7;
    const int nwg = gridDim.x;
    int bx = blockIdx.x;
    if ((nwg & 7) == 0) bx = (bx & 7) * (nwg >> 3) + (bx >> 3);
    const int bm = bx / nb, bn = bx % nb;
    const int m0 = bm << 7, n0 = bn << 7;

    const int srow = tid >> 2;
    const int scol = (tid & 3) << 3;
    const bf16* Asrc = A + (size_t)(m0 + srow) * K + scol;
    const bf16* Bsrc = Bt + (size_t)(n0 + srow) * K + scol;
    const size_t rstep = (size_t)64 * K;

    const int lr = lane & 15, lg = lane >> 4;
    const int aoff = (wr * 64 + lr) * 32 + lg * 8;
    const int boff = (wc * 64 + lr) * 32 + lg * 8;

#define STG(buf, k0)                                                \
    do {                                                            \
        gl_lds16(Asrc + (k0),         &As[buf][wv * 512]);          \
        gl_lds16(Asrc + (k0) + rstep, &As[buf][wv * 512 + 2048]);   \
        gl_lds16(Bsrc + (k0),         &Bs[buf][wv * 512]);          \
        gl_lds16(Bsrc + (k0) + rstep, &Bs[buf][wv * 512 + 2048]);   \
    } while (0)

    f32x4 acc00 = {}, acc01 = {}, acc02 = {}, acc03 = {};
    f32x4 acc10 = {}, acc11 = {}, acc12 = {}, acc13 = {};
    f32x4 acc20 = {}, acc21 = {}, acc22 = {}, acc23 = {};
    f32x4 acc30 = {}, acc31 = {}, acc32 = {}, acc33 = {};

    const int NT = K >> 5;
    STG(0, 0);
    STG(1, 32);
    for (int t = 0; t < NT; ++t) {
        if (t + 1 < NT) asm volatile("s_waitcnt vmcnt(4)" ::: "memory");
        else            asm volatile("s_waitcnt vmcnt(0)" ::: "memory");
        __builtin_amdgcn_s_barrier();
        asm volatile("" ::: "memory");
        const bf16* Ab = As[t & 1];
        const bf16* Bb = Bs[t & 1];
        bf16x8 af0 = *(const bf16x8*)&Ab[aoff];
        bf16x8 af1 = *(const bf16x8*)&Ab[aoff + 512];
        bf16x8 af2 = *(const bf16x8*)&Ab[aoff + 1024];
        bf16x8 af3 = *(const bf16x8*)&Ab[aoff + 1536];
        bf16x8 bf0 = *(const bf16x8*)&Bb[boff];
        bf16x8 bf1 = *(const bf16x8*)&Bb[boff + 512];
        bf16x8 bf2 = *(const bf16x8*)&Bb[boff + 1024];
        bf16x8 bf3 = *(const bf16x8*)&Bb[boff + 1536];
        MF(af0, bf0, acc00); MF(af0, bf1, acc01); MF(af0, bf2, acc02); MF(af0, bf3, acc03);
        MF(af1, bf0, acc10); MF(af1, bf1, acc11); MF(af1, bf2, acc12); MF(af1, bf3, acc13);
        MF(af2, bf0, acc20); MF(af2, bf1, acc21); MF(af2, bf2, acc22); MF(af2, bf3, acc23);
        MF(af3, bf0, acc30); MF(af3, bf1, acc31); MF(af3, bf2, acc32); MF(af3, bf3, acc33);
        __builtin_amdgcn_s_barrier();
        asm volatile("" ::: "memory");
        if (t + 2 < NT) STG(t & 1, (t + 2) << 5);
    }
#undef STG

#define EPI(mi, ni, ACC)                                                        \
    do {                                                                        \
        const int gmb = m0 + wr * 64 + mi * 16 + 4 * lg;                        \
        const int gn = n0 + wc * 64 + ni * 16 + lr;                             \
        const float bia = bias[gn];                                             \
        _Pragma("unroll")                                                       \
        for (int i = 0; i < 4; ++i) {                                           \
            float v = ACC[i] + bia;                                             \
            const int row = gmb + i;                                            \
            if (MODE == 0) {                                                    \
                if (gn < 512) ((float*)Cout)[(size_t)row * 512 + gn] = v;       \
                else ((bf16*)Cout2)[(size_t)row * 1536 + (gn - 512)] = (bf16)v; \
            } else if (MODE == 1) {                                             \
                const float ge = 0.5f * v * (1.0f + erff(v * 0.70710678118654752f)); \
                ((bf16*)Cout)[(size_t)row * N + gn] = (bf16)ge;                 \
            } else {                                                            \
                const size_t off = (size_t)row * N + gn;                        \
                ((float*)Cout)[off] = v + add1[off] + add2[off];                \
            }                                                                   \
        }                                                                       \
    } while (0)
    EPI(0, 0, acc00); EPI(0, 1, acc01); EPI(0, 2, acc02); EPI(0, 3, acc03);
    EPI(1, 0, acc10); EPI(1, 1, acc11); EPI(1, 2, acc12); EPI(1, 3, acc13);
    EPI(2, 0, acc20); EPI(2, 1, acc21); EPI(2, 2, acc22); EPI(2, 3, acc23);
    EPI(3, 0, acc30); EPI(3, 1, acc31); EPI(3, 2, acc32); EPI(3, 3, acc33);
#undef EPI
}

// ---------------------------------------------------------------- p_scalar
__global__ __launch_bounds__(256) void pscalar_kernel(const float* __restrict__ linp,
                                                      float* __restrict__ ps) {
    const int row = blockIdx.x * 4 + (threadIdx.x >> 6);
    const int lane = threadIdx.x & 63;
    const float* pr = linp + (size_t)row * 512 + lane * 8;
    float s = 0.f;
#pragma unroll
    for (int i = 0; i < 8; ++i) {
        const float v = pr[i];
        s += __builtin_amdgcn_rcpf(1.f + __expf(-v));
    }
#pragma unroll
    for (int o = 32; o; o >>= 1) s += __shfl_down(s, o);
    if (!lane) ps[row] = s * (1.f / 512.f);
}

// ---------------------------------------------------------------- scan
#define SCL 16
__global__ __launch_bounds__(256) void scan_kernel(const float* __restrict__ linp,
                                                   const bf16* __restrict__ lint,
                                                   float* __restrict__ h_re) {
    const int blk = blockIdx.x;
    const int dh = blk & 1;
    const int tc = (blk >> 1) & 255;
    const int b = blk >> 9;
    const int d = dh * 256 + threadIdx.x;
    const int t0 = tc * SCL;

    float par[13], pai[13], pbr[13], pbi[13];
#pragma unroll
    for (int k = 0; k < 13; ++k) { par[k] = 0.f; pai[k] = 0.f; pbr[k] = 0.f; pbi[k] = 0.f; }

    const int warm = (tc == 0) ? 0 : 13;
    const float* pp = linp + (size_t)(b * TT + t0 - warm) * 512 + d;
    const bf16* tp = lint + (size_t)(b * TT + t0 - warm) * 1536 + d;
    float* pout = h_re + ((size_t)(b * TT + t0)) * DD + d;

#define XFORM(car, cai, cbr, cbi)                                        \
    const float pl = pp[0];                                              \
    const float th = (float)tp[0];                                       \
    const float re = (float)tp[512];                                     \
    const float im = (float)tp[1024];                                    \
    pp += 512; tp += 1536;                                               \
    const float om = __builtin_amdgcn_rcpf(1.f + __expf(pl));            \
    float fr_, sn, cs;                                                   \
    { const float rv_ = th * 0.15915494309189535f;                       \
      asm("v_fract_f32 %0, %1" : "=v"(fr_) : "v"(rv_));                  \
      asm("v_sin_f32 %0, %1" : "=v"(sn) : "v"(fr_));                     \
      asm("v_cos_f32 %0, %1" : "=v"(cs) : "v"(fr_)); }                   \
    float car = om * cs, cai = om * sn, cbr = re, cbi = im;

    for (int s = 0; s < warm; ++s) {
        XFORM(car, cai, cbr, cbi)
#pragma unroll
        for (int k = 0; k < 13; ++k) {
            const float tar = par[k], tai = pai[k], tbr = pbr[k], tbi = pbi[k];
            par[k] = car; pai[k] = cai; pbr[k] = cbr; pbi[k] = cbi;
            const float nbr = car * tbr - cai * tbi + cbr;
            const float nbi = car * tbi + cai * tbr + cbi;
            if (k < 12) {
                const float nar = car * tar - cai * tai;
                const float nai = car * tai + cai * tar;
                car = nar; cai = nai;
            }
            cbr = nbr; cbi = nbi;
        }
    }

#pragma unroll 4
    for (int s = 0; s < SCL; ++s) {
        const int t = t0 + s;
        XFORM(car, cai, cbr, cbi)
        if (t == 0) {
#pragma unroll
            for (int k = 0; k < 13; ++k) { par[k] = car; pai[k] = cai; pbr[k] = cbr; pbi[k] = cbi; }
        } else {
#pragma unroll
            for (int k = 0; k < 13; ++k) {
                const float tar = par[k], tai = pai[k], tbr = pbr[k], tbi = pbi[k];
                par[k] = car; pai[k] = cai; pbr[k] = cbr; pbi[k] = cbi;
                const float nbr = car * tbr - cai * tbi + cbr;
                const float nbi = car * tbi + cai * tbr + cbi;
                if (k < 12) {
                    const float nar = car * tar - cai * tai;
                    const float nai = car * tai + cai * tar;
                    car = nar; cai = nai;
                }
                cbr = nbr; cbi = nbi;
            }
        }
        pout[(size_t)s * DD] = cbr;
    }
#undef XFORM
}

// ---------------------------------------------------------------- h_mean partials
__global__ __launch_bounds__(256) void hmean_kernel(const float* __restrict__ h_re,
                                                    float* __restrict__ hsum) {
    const int blk = blockIdx.x;
    const int b = blk >> 6;
    const int dh = (blk >> 5) & 1;
    const int tc = blk & 31;
    const int d = dh * 256 + threadIdx.x;
    float s = 0.f;
    const float* p = h_re + ((size_t)(b * TT + tc * 128)) * DD + d;
    for (int t = 0; t < 128; ++t) s += p[(size_t)t * DD];
    atomicAdd(&hsum[b * DD + d], s);
}

// ---------------------------------------------------------------- top-16
__global__ __launch_bounds__(256) void topk_kernel(const float* __restrict__ ps,
                                                   int* __restrict__ idx_out) {
    __shared__ float vals[TT];
    __shared__ float rv[4];
    __shared__ int ri[4];
    const int b = blockIdx.x, tid = threadIdx.x;
    for (int i = tid; i < TT; i += 256) vals[i] = ps[b * TT + i];
    __syncthreads();
    for (int kk = 0; kk < 16; ++kk) {
        float bv = -1e30f; int bi = 0x7fffffff;
        for (int i = tid; i < TT; i += 256) {
            const float v = vals[i];
            if (v > bv || (v == bv && i < bi)) { bv = v; bi = i; }
        }
#pragma unroll
        for (int o = 32; o; o >>= 1) {
            const float ov = __shfl_down(bv, o);
            const int oi = __shfl_down(bi, o);
            if (ov > bv || (ov == bv && oi < bi)) { bv = ov; bi = oi; }
        }
        const int lane = tid & 63, wid = tid >> 6;
        if (!lane) { rv[wid] = bv; ri[wid] = bi; }
        __syncthreads();
        if (!tid) {
            float fbv = rv[0]; int fbi = ri[0];
            for (int w = 1; w < 4; ++w)
                if (rv[w] > fbv || (rv[w] == fbv && ri[w] < fbi)) { fbv = rv[w]; fbi = ri[w]; }
            idx_out[b * 16 + kk] = fbi;
            vals[fbi] = -1e30f;
        }
        __syncthreads();
    }
}

// ---------------------------------------------------------------- keys/values
__global__ __launch_bounds__(256) void kv_kernel(
    const float* __restrict__ h_re, const int* __restrict__ tki,
    const float* __restrict__ Wk, const float* __restrict__ Wkb,
    const float* __restrict__ Wv, const float* __restrict__ Wvb,
    float* __restrict__ keys, float* __restrict__ vals) {
    const int blk = blockIdx.x;
    const int b = blk >> 4, j = blk & 15;
    const int tid = threadIdx.x;
    __shared__ float hrow[512];
    const int row = tki[b * 16 + j];
    for (int i = tid; i < 512; i += 256)
        hrow[i] = h_re[((size_t)(b * TT + row)) * DD + i];
    __syncthreads();
    for (int n = tid; n < 512; n += 256) {
        float sk = Wkb[n], sv = Wvb[n];
        for (int k = 0; k < 512; ++k) {
            const float h = hrow[k];
            sk += h * Wk[(size_t)k * 512 + n];
            sv += h * Wv[(size_t)k * 512 + n];
        }
        keys[((size_t)(b * 16 + j)) * 512 + n] = sk;
        vals[((size_t)(b * 16 + j)) * 512 + n] = sv;
    }
}

// ---------------------------------------------------------------- query/gate/attn/out
__global__ __launch_bounds__(256) void attn_out_kernel(
    const float* __restrict__ hsum, const float* __restrict__ Wq,
    const float* __restrict__ Wqb, const float* __restrict__ gw,
    const float* __restrict__ gb, const float* __restrict__ keys,
    const float* __restrict__ vals, float* __restrict__ out1) {
    const int b = blockIdx.x, tid = threadIdx.x;
    const int lane = tid & 63, wid = tid >> 6;
    __shared__ float hm[512];
    __shared__ float q[512];
    __shared__ float sc[16];
    __shared__ float red[4];
    for (int d0 = tid; d0 < 512; d0 += 256)
        hm[d0] = hsum[b * 512 + d0] * (1.f / 4096.f);
    __syncthreads();
    for (int n = tid; n < 512; n += 256) {
        float s = Wqb[n];
        for (int k = 0; k < 512; ++k) s += hm[k] * Wq[(size_t)k * 512 + n];
        q[n] = s;
    }
    float gp = 0.f;
    for (int k = tid; k < 512; k += 256) gp += hm[k] * gw[k];
#pragma unroll
    for (int o = 32; o; o >>= 1) gp += __shfl_down(gp, o);
    if (!lane) red[wid] = gp;
    __syncthreads();
    const float g = 1.f / (1.f + __expf(-(red[0] + red[1] + red[2] + red[3] + gb[0])));
    for (int kk = wid; kk < 16; kk += 4) {
        float sp = 0.f;
        const float* kr = keys + ((size_t)(b * 16 + kk)) * 512;
        for (int k2 = lane; k2 < 512; k2 += 64) sp += q[k2] * kr[k2];
#pragma unroll
        for (int o = 32; o; o >>= 1) sp += __shfl_down(sp, o);
        if (!lane) sc[kk] = sp * 0.04419417382415922f;
    }
    __syncthreads();
    float mx = sc[0];
#pragma unroll
    for (int kk = 1; kk < 16; ++kk) mx = fmaxf(mx, sc[kk]);
    float den = 0.f;
    float w16[16];
#pragma unroll
    for (int kk = 0; kk < 16; ++kk) { w16[kk] = __expf(sc[kk] - mx); den += w16[kk]; }
    const float rden = 1.f / den;
    for (int d0 = tid; d0 < 512; d0 += 256) {
        float co = 0.f;
#pragma unroll
        for (int kk = 0; kk < 16; ++kk)
            co += w16[kk] * vals[((size_t)(b * 16 + kk)) * 512 + d0];
        out1[b * 512 + d0] = hm[d0] + g * (co * rden);
    }
}

// ---------------------------------------------------------------- launch
extern "C" void kernel_launch(void* const* d_in, const int* in_sizes, int n_in,
                              void* d_out, int out_size, void* d_ws, size_t ws_size,
                              hipStream_t stream) {
    const float* x    = (const float*)d_in[0];
    const float* ln1g = (const float*)d_in[1];
    const float* ln1b = (const float*)d_in[2];
    const float* ln2g = (const float*)d_in[3];
    const float* ln2b = (const float*)d_in[4];
    const float* Wp_w = (const float*)d_in[5];
    const float* Wp_b = (const float*)d_in[6];
    const float* Wt_w = (const float*)d_in[7];
    const float* Wt_b = (const float*)d_in[8];
    const float* Wr_w = (const float*)d_in[9];
    const float* Wr_b = (const float*)d_in[10];
    const float* Wi_w = (const float*)d_in[11];
    const float* Wi_b = (const float*)d_in[12];
    const float* Wk_w = (const float*)d_in[13];
    const float* Wk_b = (const float*)d_in[14];
    const float* Wv_w = (const float*)d_in[15];
    const float* Wv_b = (const float*)d_in[16];
    const float* Wq_w = (const float*)d_in[17];
    const float* Wq_b = (const float*)d_in[18];
    const float* gw   = (const float*)d_in[19];
    const float* gb   = (const float*)d_in[20];
    const float* f1w  = (const float*)d_in[21];
    const float* f1b  = (const float*)d_in[22];
    const float* f2w  = (const float*)d_in[23];
    const float* f2b  = (const float*)d_in[24];

    char* wsp = (char*)d_ws;
    float* linp = (float*)wsp;                       // [M][512]  f32 (33.5MB)
    bf16* lint = (bf16*)(wsp + 33554432);            // [M][1536] bf16 (50.3MB)
    char* p = wsp + 83886080;
    float* h_re = (float*)p; p += 33554432;          // [M][512] f32
    bf16* xn = (bf16*)p;     p += 16777216;          // [M][512] bf16
    bf16* hn = (bf16*)p;     p += 16777216;          // [M][512] bf16
    bf16* wcat = (bf16*)p;   p += 2097152;           // [2048][512] bf16 (Bt)
    bf16* f1bt = (bf16*)p;   p += 2097152;           // [2048][512] bf16
    bf16* f2bt = (bf16*)p;   p += 2097152;           // [512][2048] bf16
    float* bcat = (float*)p; p += 8192;              // [2048]
    float* ps = (float*)p;   p += 65536;             // [B][T]
    float* hsum = (float*)p; p += 8192;              // [B][512]
    int* tki = (int*)p;      p += 256;               // [B][16]
    float* keys = (float*)p; p += 131072;            // [B][16][512]
    float* valsb = (float*)p;                        // [B][16][512]
    bf16* act = (bf16*)wsp;                          // [M][2048] bf16 overlays linp+lint
    float* out0 = (float*)d_out;
    float* out1 = (float*)d_out + OUT1_OFF;

    dim3 tb(32, 8);
    transpose_bf16<<<dim3(16, 16), tb, 0, stream>>>(Wp_w, wcat + (size_t)0 * 512 * 512, 512, 512);
    transpose_bf16<<<dim3(16, 16), tb, 0, stream>>>(Wt_w, wcat + (size_t)1 * 512 * 512, 512, 512);
    transpose_bf16<<<dim3(16, 16), tb, 0, stream>>>(Wr_w, wcat + (size_t)2 * 512 * 512, 512, 512);
    transpose_bf16<<<dim3(16, 16), tb, 0, stream>>>(Wi_w, wcat + (size_t)3 * 512 * 512, 512, 512);
    transpose_bf16<<<dim3(64, 16), tb, 0, stream>>>(f1w, f1bt, 512, 2048);
    transpose_bf16<<<dim3(16, 64), tb, 0, stream>>>(f2w, f2bt, 2048, 512);
    pack_bias<<<8, 256, 0, stream>>>(Wp_b, Wt_b, Wr_b, Wi_b, bcat);

    // LN1 -> xn
    ln_kernel<<<4096, 256, 0, stream>>>(x, nullptr, ln1g, ln1b, xn);
    // fused 4-projection GEMM (8-phase 256^2): p-logits f32 -> linp ; theta/re/im bf16 -> lint
    gemm8p<0><<<512, 512, 0, stream>>>(xn, wcat, bcat, linp, lint, MM, 2048, 512);
    // p_scalar rows
    pscalar_kernel<<<4096, 256, 0, stream>>>(linp, ps);
    // 13-stage pipeline scan -> h_re
    scan_kernel<<<2048, 256, 0, stream>>>(linp, lint, h_re);
    // h_mean partial sums
    zero_kernel<<<8, 256, 0, stream>>>(hsum, 2048);
    hmean_kernel<<<256, 256, 0, stream>>>(h_re, hsum);
    // cache path
    topk_kernel<<<4, 256, 0, stream>>>(ps, tki);
    kv_kernel<<<64, 256, 0, stream>>>(h_re, tki, Wk_w, Wk_b, Wv_w, Wv_b, keys, valsb);
    attn_out_kernel<<<4, 256, 0, stream>>>(hsum, Wq_w, Wq_b, gw, gb, keys, valsb, out1);
    // FFN path (act overlays linp/lint -- safe: scan+pscalar already consumed them)
    ln_kernel<<<4096, 256, 0, stream>>>(h_re, x, ln2g, ln2b, hn);
    gemm8p<1><<<512, 512, 0, stream>>>(hn, f1bt, f1b, act, nullptr, MM, 2048, 512);
    gemm_bt<2><<<512, 256, 0, stream>>>(act, f2bt, f2b, out0, nullptr, h_re, x, MM, 512, 2048);
}

// Round 10
// 428.193 us; speedup vs baseline: 1.1550x; 1.1550x over previous
//
#include <hip/hip_runtime.h>
#include <hip/hip_bf16.h>
#include <cstdint>
#include <cstddef>

typedef __bf16 bf16;
typedef __attribute__((ext_vector_type(8))) __bf16 bf16x8;
typedef __attribute__((ext_vector_type(4))) float f32x4;

#define BB 4
#define TT 4096
#define DD 512
#define MM (BB * TT)              // 16384 rows
#define OUT1_OFF ((size_t)MM * DD)

typedef __attribute__((address_space(1))) void as1_void;
typedef __attribute__((address_space(3))) void as3_void;

__device__ __forceinline__ void gl_lds16(const void* g, void* l) {
    __builtin_amdgcn_global_load_lds((as1_void*)(uintptr_t)g,
                                     (as3_void*)(uintptr_t)l, 16, 0, 0);
}

// ---------------------------------------------------------------- transpose
__global__ void transpose_bf16(const float* __restrict__ in, bf16* __restrict__ out,
                               int R, int C) {
    __shared__ float tile[32][33];
    const int c0 = blockIdx.x * 32, r0 = blockIdx.y * 32;
    const int tx = threadIdx.x, ty = threadIdx.y;
#pragma unroll
    for (int i = 0; i < 32; i += 8)
        tile[ty + i][tx] = in[(size_t)(r0 + ty + i) * C + (c0 + tx)];
    __syncthreads();
#pragma unroll
    for (int i = 0; i < 32; i += 8)
        out[(size_t)(c0 + ty + i) * R + (r0 + tx)] = (bf16)tile[tx][ty + i];
}

__global__ void pack_bias(const float* __restrict__ a, const float* __restrict__ b,
                          const float* __restrict__ c, const float* __restrict__ d,
                          float* __restrict__ o) {
    const int i = blockIdx.x * 256 + threadIdx.x;
    if (i < 2048) {
        const float* s = (i < 512) ? a : (i < 1024) ? b : (i < 1536) ? c : d;
        o[i] = s[i & 511];
    }
}

__global__ void zero_kernel(float* __restrict__ p, int n) {
    const int i = blockIdx.x * 256 + threadIdx.x;
    if (i < n) p[i] = 0.f;
}

// ---------------------------------------------------------------- layernorm
__global__ __launch_bounds__(256) void ln_kernel(
    const float* __restrict__ X, const float* __restrict__ Xadd,
    const float* __restrict__ gw, const float* __restrict__ bw,
    bf16* __restrict__ out) {
    const int row = blockIdx.x * 4 + (threadIdx.x >> 6);
    const int lane = threadIdx.x & 63;
    const float* xr = X + (size_t)row * DD + lane * 8;
    float v[8];
    float4 v0 = *(const float4*)xr;
    float4 v1 = *(const float4*)(xr + 4);
    v[0] = v0.x; v[1] = v0.y; v[2] = v0.z; v[3] = v0.w;
    v[4] = v1.x; v[5] = v1.y; v[6] = v1.z; v[7] = v1.w;
    if (Xadd) {
        const float* ad = Xadd + (size_t)row * DD + lane * 8;
        float4 a0 = *(const float4*)ad;
        float4 a1 = *(const float4*)(ad + 4);
        v[0] += a0.x; v[1] += a0.y; v[2] += a0.z; v[3] += a0.w;
        v[4] += a1.x; v[5] += a1.y; v[6] += a1.z; v[7] += a1.w;
    }
    float s = 0.f, ss = 0.f;
#pragma unroll
    for (int i = 0; i < 8; ++i) { s += v[i]; ss += v[i] * v[i]; }
#pragma unroll
    for (int o = 32; o; o >>= 1) { s += __shfl_down(s, o); ss += __shfl_down(ss, o); }
    s = __shfl(s, 0); ss = __shfl(ss, 0);
    const float mu = s * (1.f / DD);
    const float var = ss * (1.f / DD) - mu * mu;
    const float rstd = rsqrtf(var + 1e-5f);
    bf16x8 o8;
#pragma unroll
    for (int i = 0; i < 8; ++i)
        o8[i] = (bf16)((v[i] - mu) * rstd * gw[lane * 8 + i] + bw[lane * 8 + i]);
    *(bf16x8*)(out + (size_t)row * DD + lane * 8) = o8;
}

#define MF(a_, b_, c_) c_ = __builtin_amdgcn_mfma_f32_16x16x32_bf16(a_, b_, c_, 0, 0, 0)

// ---------------------------------------------------------------- GEMM (bf16 MFMA)
// R6 kernel + T2 both-sides XOR swizzle. 128x128/4-wave/BK=32, counted-vmcnt
// 2-deep pipeline. Rows are 64B = 4 x 16B slots; involution
//   phys_slot = log_slot ^ ((row>>1)&3)
// breaks the 8-way frag-read conflict (lr lanes at stride 64B) down to the
// free 2-way. Staging keeps a LINEAR gl_lds dest; the inverse permutation is
// applied on the GLOBAL source column (rule 21). Read side applies the same
// XOR; invariant across mi*16 row offsets and the +64-row staging line.
// MODE 0: f32 cols<512 -> Cout (linp); bf16 cols>=512 -> Cout2 (lint)
// MODE 1: bf16 out = gelu(acc + bias)
// MODE 2: f32 out = acc + bias + add1 + add2
template <int MODE>
__global__ __launch_bounds__(256) void gemm_bt(
    const bf16* __restrict__ A, const bf16* __restrict__ Bt,
    const float* __restrict__ bias, void* __restrict__ Cout,
    void* __restrict__ Cout2,
    const float* __restrict__ add1, const float* __restrict__ add2,
    int M, int N, int K) {
    __shared__ bf16 As[2][4096];
    __shared__ bf16 Bs[2][4096];
    const int tid = threadIdx.x;
    const int lane = tid & 63;
    const int wv = tid >> 6;
    const int wr = wv >> 1, wc = wv & 1;
    const int nb = N >> 7;
    const int nwg = gridDim.x;
    int bx = blockIdx.x;
    if ((nwg & 7) == 0) bx = (bx & 7) * (nwg >> 3) + (bx >> 3);  // XCD swizzle
    const int bm = bx / nb, bn = bx % nb;
    const int m0 = bm << 7, n0 = bn << 7;

    const int srow = tid >> 2;                              // staging row (0..63)
    const int scol = (((tid & 3) ^ ((tid >> 3) & 3)) << 3); // pre-swizzled global col
    const bf16* Asrc = A + (size_t)(m0 + srow) * K + scol;
    const bf16* Bsrc = Bt + (size_t)(n0 + srow) * K + scol;
    const size_t rstep = (size_t)64 * K;

    const int lr = lane & 15, lg = lane >> 4;
    const int sel = ((lg ^ ((lr >> 1) & 3)) << 3);          // swizzled 16B slot
    const int aoff = (wr * 64 + lr) * 32 + sel;
    const int boff = (wc * 64 + lr) * 32 + sel;

#define STG(buf, k0)                                                \
    do {                                                            \
        gl_lds16(Asrc + (k0),         &As[buf][wv * 512]);          \
        gl_lds16(Asrc + (k0) + rstep, &As[buf][wv * 512 + 2048]);   \
        gl_lds16(Bsrc + (k0),         &Bs[buf][wv * 512]);          \
        gl_lds16(Bsrc + (k0) + rstep, &Bs[buf][wv * 512 + 2048]);   \
    } while (0)

    f32x4 acc00 = {}, acc01 = {}, acc02 = {}, acc03 = {};
    f32x4 acc10 = {}, acc11 = {}, acc12 = {}, acc13 = {};
    f32x4 acc20 = {}, acc21 = {}, acc22 = {}, acc23 = {};
    f32x4 acc30 = {}, acc31 = {}, acc32 = {}, acc33 = {};

    const int NT = K >> 5;
    STG(0, 0);
    STG(1, 32);
    for (int t = 0; t < NT; ++t) {
        if (t + 1 < NT) asm volatile("s_waitcnt vmcnt(4)" ::: "memory");
        else            asm volatile("s_waitcnt vmcnt(0)" ::: "memory");
        __builtin_amdgcn_s_barrier();
        asm volatile("" ::: "memory");
        const bf16* Ab = As[t & 1];
        const bf16* Bb = Bs[t & 1];
        bf16x8 af0 = *(const bf16x8*)&Ab[aoff];
        bf16x8 af1 = *(const bf16x8*)&Ab[aoff + 512];
        bf16x8 af2 = *(const bf16x8*)&Ab[aoff + 1024];
        bf16x8 af3 = *(const bf16x8*)&Ab[aoff + 1536];
        bf16x8 bf0 = *(const bf16x8*)&Bb[boff];
        bf16x8 bf1 = *(const bf16x8*)&Bb[boff + 512];
        bf16x8 bf2 = *(const bf16x8*)&Bb[boff + 1024];
        bf16x8 bf3 = *(const bf16x8*)&Bb[boff + 1536];
        MF(af0, bf0, acc00); MF(af0, bf1, acc01); MF(af0, bf2, acc02); MF(af0, bf3, acc03);
        MF(af1, bf0, acc10); MF(af1, bf1, acc11); MF(af1, bf2, acc12); MF(af1, bf3, acc13);
        MF(af2, bf0, acc20); MF(af2, bf1, acc21); MF(af2, bf2, acc22); MF(af2, bf3, acc23);
        MF(af3, bf0, acc30); MF(af3, bf1, acc31); MF(af3, bf2, acc32); MF(af3, bf3, acc33);
        __builtin_amdgcn_s_barrier();
        asm volatile("" ::: "memory");
        if (t + 2 < NT) STG(t & 1, (t + 2) << 5);
    }
#undef STG

#define EPI(mi, ni, ACC)                                                        \
    do {                                                                        \
        const int gmb = m0 + wr * 64 + mi * 16 + 4 * lg;                        \
        const int gn = n0 + wc * 64 + ni * 16 + lr;                             \
        const float bia = bias[gn];                                             \
        _Pragma("unroll")                                                       \
        for (int i = 0; i < 4; ++i) {                                           \
            float v = ACC[i] + bia;                                             \
            const int row = gmb + i;                                            \
            if (MODE == 0) {                                                    \
                if (gn < 512) ((float*)Cout)[(size_t)row * 512 + gn] = v;       \
                else ((bf16*)Cout2)[(size_t)row * 1536 + (gn - 512)] = (bf16)v; \
            } else if (MODE == 1) {                                             \
                const float ge = 0.5f * v * (1.0f + erff(v * 0.70710678118654752f)); \
                ((bf16*)Cout)[(size_t)row * N + gn] = (bf16)ge;                 \
            } else {                                                            \
                const size_t off = (size_t)row * N + gn;                        \
                ((float*)Cout)[off] = v + add1[off] + add2[off];                \
            }                                                                   \
        }                                                                       \
    } while (0)
    EPI(0, 0, acc00); EPI(0, 1, acc01); EPI(0, 2, acc02); EPI(0, 3, acc03);
    EPI(1, 0, acc10); EPI(1, 1, acc11); EPI(1, 2, acc12); EPI(1, 3, acc13);
    EPI(2, 0, acc20); EPI(2, 1, acc21); EPI(2, 2, acc22); EPI(2, 3, acc23);
    EPI(3, 0, acc30); EPI(3, 1, acc31); EPI(3, 2, acc32); EPI(3, 3, acc33);
#undef EPI
}

// ---------------------------------------------------------------- p_scalar
__global__ __launch_bounds__(256) void pscalar_kernel(const float* __restrict__ linp,
                                                      float* __restrict__ ps) {
    const int row = blockIdx.x * 4 + (threadIdx.x >> 6);
    const int lane = threadIdx.x & 63;
    const float* pr = linp + (size_t)row * 512 + lane * 8;
    float s = 0.f;
#pragma unroll
    for (int i = 0; i < 8; ++i) {
        const float v = pr[i];
        s += __builtin_amdgcn_rcpf(1.f + __expf(-v));
    }
#pragma unroll
    for (int o = 32; o; o >>= 1) s += __shfl_down(s, o);
    if (!lane) ps[row] = s * (1.f / 512.f);
}

// ---------------------------------------------------------------- scan
#define SCL 16
__global__ __launch_bounds__(256) void scan_kernel(const float* __restrict__ linp,
                                                   const bf16* __restrict__ lint,
                                                   float* __restrict__ h_re) {
    const int blk = blockIdx.x;
    const int dh = blk & 1;
    const int tc = (blk >> 1) & 255;
    const int b = blk >> 9;
    const int d = dh * 256 + threadIdx.x;
    const int t0 = tc * SCL;

    float par[13], pai[13], pbr[13], pbi[13];
#pragma unroll
    for (int k = 0; k < 13; ++k) { par[k] = 0.f; pai[k] = 0.f; pbr[k] = 0.f; pbi[k] = 0.f; }

    const int warm = (tc == 0) ? 0 : 13;
    const float* pp = linp + (size_t)(b * TT + t0 - warm) * 512 + d;
    const bf16* tp = lint + (size_t)(b * TT + t0 - warm) * 1536 + d;
    float* pout = h_re + ((size_t)(b * TT + t0)) * DD + d;

#define XFORM(car, cai, cbr, cbi)                                        \
    const float pl = pp[0];                                              \
    const float th = (float)tp[0];                                       \
    const float re = (float)tp[512];                                     \
    const float im = (float)tp[1024];                                    \
    pp += 512; tp += 1536;                                               \
    const float om = __builtin_amdgcn_rcpf(1.f + __expf(pl));            \
    float fr_, sn, cs;                                                   \
    { const float rv_ = th * 0.15915494309189535f;                       \
      asm("v_fract_f32 %0, %1" : "=v"(fr_) : "v"(rv_));                  \
      asm("v_sin_f32 %0, %1" : "=v"(sn) : "v"(fr_));                     \
      asm("v_cos_f32 %0, %1" : "=v"(cs) : "v"(fr_)); }                   \
    float car = om * cs, cai = om * sn, cbr = re, cbi = im;

    for (int s = 0; s < warm; ++s) {
        XFORM(car, cai, cbr, cbi)
#pragma unroll
        for (int k = 0; k < 13; ++k) {
            const float tar = par[k], tai = pai[k], tbr = pbr[k], tbi = pbi[k];
            par[k] = car; pai[k] = cai; pbr[k] = cbr; pbi[k] = cbi;
            const float nbr = car * tbr - cai * tbi + cbr;
            const float nbi = car * tbi + cai * tbr + cbi;
            if (k < 12) {
                const float nar = car * tar - cai * tai;
                const float nai = car * tai + cai * tar;
                car = nar; cai = nai;
            }
            cbr = nbr; cbi = nbi;
        }
    }

#pragma unroll 4
    for (int s = 0; s < SCL; ++s) {
        const int t = t0 + s;
        XFORM(car, cai, cbr, cbi)
        if (t == 0) {
#pragma unroll
            for (int k = 0; k < 13; ++k) { par[k] = car; pai[k] = cai; pbr[k] = cbr; pbi[k] = cbi; }
        } else {
#pragma unroll
            for (int k = 0; k < 13; ++k) {
                const float tar = par[k], tai = pai[k], tbr = pbr[k], tbi = pbi[k];
                par[k] = car; pai[k] = cai; pbr[k] = cbr; pbi[k] = cbi;
                const float nbr = car * tbr - cai * tbi + cbr;
                const float nbi = car * tbi + cai * tbr + cbi;
                if (k < 12) {
                    const float nar = car * tar - cai * tai;
                    const float nai = car * tai + cai * tar;
                    car = nar; cai = nai;
                }
                cbr = nbr; cbi = nbi;
            }
        }
        pout[(size_t)s * DD] = cbr;
    }
#undef XFORM
}

// ---------------------------------------------------------------- h_mean partials
__global__ __launch_bounds__(256) void hmean_kernel(const float* __restrict__ h_re,
                                                    float* __restrict__ hsum) {
    const int blk = blockIdx.x;
    const int b = blk >> 6;
    const int dh = (blk >> 5) & 1;
    const int tc = blk & 31;
    const int d = dh * 256 + threadIdx.x;
    float s = 0.f;
    const float* p = h_re + ((size_t)(b * TT + tc * 128)) * DD + d;
    for (int t = 0; t < 128; ++t) s += p[(size_t)t * DD];
    atomicAdd(&hsum[b * DD + d], s);
}

// ---------------------------------------------------------------- top-16
__global__ __launch_bounds__(256) void topk_kernel(const float* __restrict__ ps,
                                                   int* __restrict__ idx_out) {
    __shared__ float vals[TT];
    __shared__ float rv[4];
    __shared__ int ri[4];
    const int b = blockIdx.x, tid = threadIdx.x;
    for (int i = tid; i < TT; i += 256) vals[i] = ps[b * TT + i];
    __syncthreads();
    for (int kk = 0; kk < 16; ++kk) {
        float bv = -1e30f; int bi = 0x7fffffff;
        for (int i = tid; i < TT; i += 256) {
            const float v = vals[i];
            if (v > bv || (v == bv && i < bi)) { bv = v; bi = i; }
        }
#pragma unroll
        for (int o = 32; o; o >>= 1) {
            const float ov = __shfl_down(bv, o);
            const int oi = __shfl_down(bi, o);
            if (ov > bv || (ov == bv && oi < bi)) { bv = ov; bi = oi; }
        }
        const int lane = tid & 63, wid = tid >> 6;
        if (!lane) { rv[wid] = bv; ri[wid] = bi; }
        __syncthreads();
        if (!tid) {
            float fbv = rv[0]; int fbi = ri[0];
            for (int w = 1; w < 4; ++w)
                if (rv[w] > fbv || (rv[w] == fbv && ri[w] < fbi)) { fbv = rv[w]; fbi = ri[w]; }
            idx_out[b * 16 + kk] = fbi;
            vals[fbi] = -1e30f;
        }
        __syncthreads();
    }
}

// ---------------------------------------------------------------- keys/values
__global__ __launch_bounds__(256) void kv_kernel(
    const float* __restrict__ h_re, const int* __restrict__ tki,
    const float* __restrict__ Wk, const float* __restrict__ Wkb,
    const float* __restrict__ Wv, const float* __restrict__ Wvb,
    float* __restrict__ keys, float* __restrict__ vals) {
    const int blk = blockIdx.x;
    const int b = blk >> 4, j = blk & 15;
    const int tid = threadIdx.x;
    __shared__ float hrow[512];
    const int row = tki[b * 16 + j];
    for (int i = tid; i < 512; i += 256)
        hrow[i] = h_re[((size_t)(b * TT + row)) * DD + i];
    __syncthreads();
    for (int n = tid; n < 512; n += 256) {
        float sk = Wkb[n], sv = Wvb[n];
        for (int k = 0; k < 512; ++k) {
            const float h = hrow[k];
            sk += h * Wk[(size_t)k * 512 + n];
            sv += h * Wv[(size_t)k * 512 + n];
        }
        keys[((size_t)(b * 16 + j)) * 512 + n] = sk;
        vals[((size_t)(b * 16 + j)) * 512 + n] = sv;
    }
}

// ---------------------------------------------------------------- query/gate/attn/out
__global__ __launch_bounds__(256) void attn_out_kernel(
    const float* __restrict__ hsum, const float* __restrict__ Wq,
    const float* __restrict__ Wqb, const float* __restrict__ gw,
    const float* __restrict__ gb, const float* __restrict__ keys,
    const float* __restrict__ vals, float* __restrict__ out1) {
    const int b = blockIdx.x, tid = threadIdx.x;
    const int lane = tid & 63, wid = tid >> 6;
    __shared__ float hm[512];
    __shared__ float q[512];
    __shared__ float sc[16];
    __shared__ float red[4];
    for (int d0 = tid; d0 < 512; d0 += 256)
        hm[d0] = hsum[b * 512 + d0] * (1.f / 4096.f);
    __syncthreads();
    for (int n = tid; n < 512; n += 256) {
        float s = Wqb[n];
        for (int k = 0; k < 512; ++k) s += hm[k] * Wq[(size_t)k * 512 + n];
        q[n] = s;
    }
    float gp = 0.f;
    for (int k = tid; k < 512; k += 256) gp += hm[k] * gw[k];
#pragma unroll
    for (int o = 32; o; o >>= 1) gp += __shfl_down(gp, o);
    if (!lane) red[wid] = gp;
    __syncthreads();
    const float g = 1.f / (1.f + __expf(-(red[0] + red[1] + red[2] + red[3] + gb[0])));
    for (int kk = wid; kk < 16; kk += 4) {
        float sp = 0.f;
        const float* kr = keys + ((size_t)(b * 16 + kk)) * 512;
        for (int k2 = lane; k2 < 512; k2 += 64) sp += q[k2] * kr[k2];
#pragma unroll
        for (int o = 32; o; o >>= 1) sp += __shfl_down(sp, o);
        if (!lane) sc[kk] = sp * 0.04419417382415922f;
    }
    __syncthreads();
    float mx = sc[0];
#pragma unroll
    for (int kk = 1; kk < 16; ++kk) mx = fmaxf(mx, sc[kk]);
    float den = 0.f;
    float w16[16];
#pragma unroll
    for (int kk = 0; kk < 16; ++kk) { w16[kk] = __expf(sc[kk] - mx); den += w16[kk]; }
    const float rden = 1.f / den;
    for (int d0 = tid; d0 < 512; d0 += 256) {
        float co = 0.f;
#pragma unroll
        for (int kk = 0; kk < 16; ++kk)
            co += w16[kk] * vals[((size_t)(b * 16 + kk)) * 512 + d0];
        out1[b * 512 + d0] = hm[d0] + g * (co * rden);
    }
}

// ---------------------------------------------------------------- launch
extern "C" void kernel_launch(void* const* d_in, const int* in_sizes, int n_in,
                              void* d_out, int out_size, void* d_ws, size_t ws_size,
                              hipStream_t stream) {
    const float* x    = (const float*)d_in[0];
    const float* ln1g = (const float*)d_in[1];
    const float* ln1b = (const float*)d_in[2];
    const float* ln2g = (const float*)d_in[3];
    const float* ln2b = (const float*)d_in[4];
    const float* Wp_w = (const float*)d_in[5];
    const float* Wp_b = (const float*)d_in[6];
    const float* Wt_w = (const float*)d_in[7];
    const float* Wt_b = (const float*)d_in[8];
    const float* Wr_w = (const float*)d_in[9];
    const float* Wr_b = (const float*)d_in[10];
    const float* Wi_w = (const float*)d_in[11];
    const float* Wi_b = (const float*)d_in[12];
    const float* Wk_w = (const float*)d_in[13];
    const float* Wk_b = (const float*)d_in[14];
    const float* Wv_w = (const float*)d_in[15];
    const float* Wv_b = (const float*)d_in[16];
    const float* Wq_w = (const float*)d_in[17];
    const float* Wq_b = (const float*)d_in[18];
    const float* gw   = (const float*)d_in[19];
    const float* gb   = (const float*)d_in[20];
    const float* f1w  = (const float*)d_in[21];
    const float* f1b  = (const float*)d_in[22];
    const float* f2w  = (const float*)d_in[23];
    const float* f2b  = (const float*)d_in[24];

    char* wsp = (char*)d_ws;
    float* linp = (float*)wsp;                       // [M][512]  f32 (33.5MB)
    bf16* lint = (bf16*)(wsp + 33554432);            // [M][1536] bf16 (50.3MB)
    char* p = wsp + 83886080;
    float* h_re = (float*)p; p += 33554432;          // [M][512] f32
    bf16* xn = (bf16*)p;     p += 16777216;          // [M][512] bf16
    bf16* hn = (bf16*)p;     p += 16777216;          // [M][512] bf16
    bf16* wcat = (bf16*)p;   p += 2097152;           // [2048][512] bf16 (Bt)
    bf16* f1bt = (bf16*)p;   p += 2097152;           // [2048][512] bf16
    bf16* f2bt = (bf16*)p;   p += 2097152;           // [512][2048] bf16
    float* bcat = (float*)p; p += 8192;              // [2048]
    float* ps = (float*)p;   p += 65536;             // [B][T]
    float* hsum = (float*)p; p += 8192;              // [B][512]
    int* tki = (int*)p;      p += 256;               // [B][16]
    float* keys = (float*)p; p += 131072;            // [B][16][512]
    float* valsb = (float*)p;                        // [B][16][512]
    bf16* act = (bf16*)wsp;                          // [M][2048] bf16 overlays linp+lint
    float* out0 = (float*)d_out;
    float* out1 = (float*)d_out + OUT1_OFF;

    dim3 tb(32, 8);
    transpose_bf16<<<dim3(16, 16), tb, 0, stream>>>(Wp_w, wcat + (size_t)0 * 512 * 512, 512, 512);
    transpose_bf16<<<dim3(16, 16), tb, 0, stream>>>(Wt_w, wcat + (size_t)1 * 512 * 512, 512, 512);
    transpose_bf16<<<dim3(16, 16), tb, 0, stream>>>(Wr_w, wcat + (size_t)2 * 512 * 512, 512, 512);
    transpose_bf16<<<dim3(16, 16), tb, 0, stream>>>(Wi_w, wcat + (size_t)3 * 512 * 512, 512, 512);
    transpose_bf16<<<dim3(64, 16), tb, 0, stream>>>(f1w, f1bt, 512, 2048);
    transpose_bf16<<<dim3(16, 64), tb, 0, stream>>>(f2w, f2bt, 2048, 512);
    pack_bias<<<8, 256, 0, stream>>>(Wp_b, Wt_b, Wr_b, Wi_b, bcat);

    // LN1 -> xn
    ln_kernel<<<4096, 256, 0, stream>>>(x, nullptr, ln1g, ln1b, xn);
    // fused 4-projection GEMM: p-logits f32 -> linp ; theta/re/im bf16 -> lint
    gemm_bt<0><<<2048, 256, 0, stream>>>(xn, wcat, bcat, linp, lint, nullptr, nullptr, MM, 2048, 512);
    // p_scalar rows
    pscalar_kernel<<<4096, 256, 0, stream>>>(linp, ps);
    // 13-stage pipeline scan -> h_re
    scan_kernel<<<2048, 256, 0, stream>>>(linp, lint, h_re);
    // h_mean partial sums
    zero_kernel<<<8, 256, 0, stream>>>(hsum, 2048);
    hmean_kernel<<<256, 256, 0, stream>>>(h_re, hsum);
    // cache path
    topk_kernel<<<4, 256, 0, stream>>>(ps, tki);
    kv_kernel<<<64, 256, 0, stream>>>(h_re, tki, Wk_w, Wk_b, Wv_w, Wv_b, keys, valsb);
    attn_out_kernel<<<4, 256, 0, stream>>>(hsum, Wq_w, Wq_b, gw, gb, keys, valsb, out1);
    // FFN path (act overlays linp/lint -- safe: scan+pscalar already consumed them)
    ln_kernel<<<4096, 256, 0, stream>>>(h_re, x, ln2g, ln2b, hn);
    gemm_bt<1><<<2048, 256, 0, stream>>>(hn, f1bt, f1b, act, nullptr, nullptr, nullptr, MM, 2048, 512);
    gemm_bt<2><<<512, 256, 0, stream>>>(act, f2bt, f2b, out0, nullptr, h_re, x, MM, 512, 2048);
}

// Round 11
// 419.542 us; speedup vs baseline: 1.1788x; 1.0206x over previous
//
#include <hip/hip_runtime.h>
#include <hip/hip_bf16.h>
#include <cstdint>
#include <cstddef>

typedef __bf16 bf16;
typedef __attribute__((ext_vector_type(8))) __bf16 bf16x8;
typedef __attribute__((ext_vector_type(4))) __bf16 bf16x4;
typedef __attribute__((ext_vector_type(4))) float f32x4;

#define BB 4
#define TT 4096
#define DD 512
#define MM (BB * TT)              // 16384 rows
#define OUT1_OFF ((size_t)MM * DD)

typedef __attribute__((address_space(1))) void as1_void;
typedef __attribute__((address_space(3))) void as3_void;

__device__ __forceinline__ void gl_lds16(const void* g, void* l) {
    __builtin_amdgcn_global_load_lds((as1_void*)(uintptr_t)g,
                                     (as3_void*)(uintptr_t)l, 16, 0, 0);
}

#define SIGM(x) (__builtin_amdgcn_rcpf(1.f + __expf(-(x))))

// ---------------------------------------------------------------- transpose
__global__ void transpose_bf16(const float* __restrict__ in, bf16* __restrict__ out,
                               int R, int C) {
    __shared__ float tile[32][33];
    const int c0 = blockIdx.x * 32, r0 = blockIdx.y * 32;
    const int tx = threadIdx.x, ty = threadIdx.y;
#pragma unroll
    for (int i = 0; i < 32; i += 8)
        tile[ty + i][tx] = in[(size_t)(r0 + ty + i) * C + (c0 + tx)];
    __syncthreads();
#pragma unroll
    for (int i = 0; i < 32; i += 8)
        out[(size_t)(c0 + ty + i) * R + (r0 + tx)] = (bf16)tile[tx][ty + i];
}

__global__ void pack_bias(const float* __restrict__ a, const float* __restrict__ b,
                          const float* __restrict__ c, const float* __restrict__ d,
                          float* __restrict__ o) {
    const int i = blockIdx.x * 256 + threadIdx.x;
    if (i < 2048) {
        const float* s = (i < 512) ? a : (i < 1024) ? b : (i < 1536) ? c : d;
        o[i] = s[i & 511];
    }
}

__global__ void zero_kernel(float* __restrict__ p, int n) {
    const int i = blockIdx.x * 256 + threadIdx.x;
    if (i < n) p[i] = 0.f;
}

// ---------------------------------------------------------------- layernorm
__global__ __launch_bounds__(256) void ln_kernel(
    const float* __restrict__ X, const float* __restrict__ Xadd,
    const float* __restrict__ gw, const float* __restrict__ bw,
    bf16* __restrict__ out) {
    const int row = blockIdx.x * 4 + (threadIdx.x >> 6);
    const int lane = threadIdx.x & 63;
    const float* xr = X + (size_t)row * DD + lane * 8;
    float v[8];
    float4 v0 = *(const float4*)xr;
    float4 v1 = *(const float4*)(xr + 4);
    v[0] = v0.x; v[1] = v0.y; v[2] = v0.z; v[3] = v0.w;
    v[4] = v1.x; v[5] = v1.y; v[6] = v1.z; v[7] = v1.w;
    if (Xadd) {
        const float* ad = Xadd + (size_t)row * DD + lane * 8;
        float4 a0 = *(const float4*)ad;
        float4 a1 = *(const float4*)(ad + 4);
        v[0] += a0.x; v[1] += a0.y; v[2] += a0.z; v[3] += a0.w;
        v[4] += a1.x; v[5] += a1.y; v[6] += a1.z; v[7] += a1.w;
    }
    float s = 0.f, ss = 0.f;
#pragma unroll
    for (int i = 0; i < 8; ++i) { s += v[i]; ss += v[i] * v[i]; }
#pragma unroll
    for (int o = 32; o; o >>= 1) { s += __shfl_down(s, o); ss += __shfl_down(ss, o); }
    s = __shfl(s, 0); ss = __shfl(ss, 0);
    const float mu = s * (1.f / DD);
    const float var = ss * (1.f / DD) - mu * mu;
    const float rstd = rsqrtf(var + 1e-5f);
    bf16x8 o8;
#pragma unroll
    for (int i = 0; i < 8; ++i)
        o8[i] = (bf16)((v[i] - mu) * rstd * gw[lane * 8 + i] + bw[lane * 8 + i]);
    *(bf16x8*)(out + (size_t)row * DD + lane * 8) = o8;
}

#define MF(a_, b_, c_) c_ = __builtin_amdgcn_mfma_f32_16x16x32_bf16(a_, b_, c_, 0, 0, 0)

// ---------------------------------------------------------------- GEMM (bf16 MFMA)
// R10-proven: 128x128/4-wave/BK=32, counted-vmcnt 2-deep pipeline, T2
// both-sides XOR swizzle (phys_slot = log_slot ^ ((row>>1)&3)).
// MODE 0: fused transform epilogue. Column classes (512 each): p/theta/re/im.
//   p-class: om = 1-sigmoid bf16 -> lint4[row][d][0]; deterministic pscalar
//            partials (shfl over lr) -> Cout2 = pspart[8][M].
//   theta/re/im: bf16 -> lint4[row][d][1/2/3].
// MODE 1: bf16 out = gelu(acc + bias)
// MODE 2: f32 out = acc + bias + add1 + add2
template <int MODE>
__global__ __launch_bounds__(256) void gemm_bt(
    const bf16* __restrict__ A, const bf16* __restrict__ Bt,
    const float* __restrict__ bias, void* __restrict__ Cout,
    void* __restrict__ Cout2,
    const float* __restrict__ add1, const float* __restrict__ add2,
    int M, int N, int K) {
    __shared__ bf16 As[2][4096];
    __shared__ bf16 Bs[2][4096];
    const int tid = threadIdx.x;
    const int lane = tid & 63;
    const int wv = tid >> 6;
    const int wr = wv >> 1, wc = wv & 1;
    const int nb = N >> 7;
    const int nwg = gridDim.x;
    int bx = blockIdx.x;
    if ((nwg & 7) == 0) bx = (bx & 7) * (nwg >> 3) + (bx >> 3);  // XCD swizzle
    const int bm = bx / nb, bn = bx % nb;
    const int m0 = bm << 7, n0 = bn << 7;

    const int srow = tid >> 2;                              // staging row (0..63)
    const int scol = (((tid & 3) ^ ((tid >> 3) & 3)) << 3); // pre-swizzled global col
    const bf16* Asrc = A + (size_t)(m0 + srow) * K + scol;
    const bf16* Bsrc = Bt + (size_t)(n0 + srow) * K + scol;
    const size_t rstep = (size_t)64 * K;

    const int lr = lane & 15, lg = lane >> 4;
    const int sel = ((lg ^ ((lr >> 1) & 3)) << 3);          // swizzled 16B slot
    const int aoff = (wr * 64 + lr) * 32 + sel;
    const int boff = (wc * 64 + lr) * 32 + sel;

#define STG(buf, k0)                                                \
    do {                                                            \
        gl_lds16(Asrc + (k0),         &As[buf][wv * 512]);          \
        gl_lds16(Asrc + (k0) + rstep, &As[buf][wv * 512 + 2048]);   \
        gl_lds16(Bsrc + (k0),         &Bs[buf][wv * 512]);          \
        gl_lds16(Bsrc + (k0) + rstep, &Bs[buf][wv * 512 + 2048]);   \
    } while (0)

    f32x4 acc00 = {}, acc01 = {}, acc02 = {}, acc03 = {};
    f32x4 acc10 = {}, acc11 = {}, acc12 = {}, acc13 = {};
    f32x4 acc20 = {}, acc21 = {}, acc22 = {}, acc23 = {};
    f32x4 acc30 = {}, acc31 = {}, acc32 = {}, acc33 = {};

    const int NT = K >> 5;
    STG(0, 0);
    STG(1, 32);
    for (int t = 0; t < NT; ++t) {
        if (t + 1 < NT) asm volatile("s_waitcnt vmcnt(4)" ::: "memory");
        else            asm volatile("s_waitcnt vmcnt(0)" ::: "memory");
        __builtin_amdgcn_s_barrier();
        asm volatile("" ::: "memory");
        const bf16* Ab = As[t & 1];
        const bf16* Bb = Bs[t & 1];
        bf16x8 af0 = *(const bf16x8*)&Ab[aoff];
        bf16x8 af1 = *(const bf16x8*)&Ab[aoff + 512];
        bf16x8 af2 = *(const bf16x8*)&Ab[aoff + 1024];
        bf16x8 af3 = *(const bf16x8*)&Ab[aoff + 1536];
        bf16x8 bf0 = *(const bf16x8*)&Bb[boff];
        bf16x8 bf1 = *(const bf16x8*)&Bb[boff + 512];
        bf16x8 bf2 = *(const bf16x8*)&Bb[boff + 1024];
        bf16x8 bf3 = *(const bf16x8*)&Bb[boff + 1536];
        MF(af0, bf0, acc00); MF(af0, bf1, acc01); MF(af0, bf2, acc02); MF(af0, bf3, acc03);
        MF(af1, bf0, acc10); MF(af1, bf1, acc11); MF(af1, bf2, acc12); MF(af1, bf3, acc13);
        MF(af2, bf0, acc20); MF(af2, bf1, acc21); MF(af2, bf2, acc22); MF(af2, bf3, acc23);
        MF(af3, bf0, acc30); MF(af3, bf1, acc31); MF(af3, bf2, acc32); MF(af3, bf3, acc33);
        __builtin_amdgcn_s_barrier();
        asm volatile("" ::: "memory");
        if (t + 2 < NT) STG(t & 1, (t + 2) << 5);
    }
#undef STG

    if constexpr (MODE == 0) {
        const int cls = n0 >> 9;                 // 0=p 1=theta 2=re 3=im
        if (cls == 0) {
            const int pidx = (n0 + wc * 64) >> 6;    // 0..7
#define EPI0(mi, A0, A1, A2, A3)                                              \
    do {                                                                      \
        const int gmb = m0 + wr * 64 + mi * 16 + 4 * lg;                      \
        const int dbase = n0 + wc * 64 + lr;                                  \
        const float b0_ = bias[dbase], b1_ = bias[dbase + 16],                \
                    b2_ = bias[dbase + 32], b3_ = bias[dbase + 48];           \
        _Pragma("unroll")                                                     \
        for (int i = 0; i < 4; ++i) {                                         \
            const int row = gmb + i;                                          \
            const float p0 = SIGM(A0[i] + b0_);                               \
            const float p1 = SIGM(A1[i] + b1_);                               \
            const float p2 = SIGM(A2[i] + b2_);                               \
            const float p3 = SIGM(A3[i] + b3_);                               \
            bf16* ob = (bf16*)Cout + (size_t)row * 2048;                      \
            ob[(size_t)dbase * 4]        = (bf16)(1.f - p0);                  \
            ob[(size_t)(dbase + 16) * 4] = (bf16)(1.f - p1);                  \
            ob[(size_t)(dbase + 32) * 4] = (bf16)(1.f - p2);                  \
            ob[(size_t)(dbase + 48) * 4] = (bf16)(1.f - p3);                  \
            float s_ = p0 + p1 + p2 + p3;                                     \
            s_ += __shfl_xor(s_, 1); s_ += __shfl_xor(s_, 2);                 \
            s_ += __shfl_xor(s_, 4); s_ += __shfl_xor(s_, 8);                 \
            if (lr == 0) ((float*)Cout2)[(size_t)pidx * MM + row] = s_;       \
        }                                                                     \
    } while (0)
            EPI0(0, acc00, acc01, acc02, acc03);
            EPI0(1, acc10, acc11, acc12, acc13);
            EPI0(2, acc20, acc21, acc22, acc23);
            EPI0(3, acc30, acc31, acc32, acc33);
#undef EPI0
        } else {
#define EPIS(mi, ni, ACC)                                                     \
    do {                                                                      \
        const int gmb = m0 + wr * 64 + mi * 16 + 4 * lg;                      \
        const int gn = n0 + wc * 64 + ni * 16 + lr;                           \
        const int dn = gn & 511;                                              \
        const float bia = bias[gn];                                           \
        _Pragma("unroll")                                                     \
        for (int i = 0; i < 4; ++i)                                           \
            ((bf16*)Cout)[((size_t)(gmb + i) * 512 + dn) * 4 + cls] =         \
                (bf16)(ACC[i] + bia);                                         \
    } while (0)
            EPIS(0, 0, acc00); EPIS(0, 1, acc01); EPIS(0, 2, acc02); EPIS(0, 3, acc03);
            EPIS(1, 0, acc10); EPIS(1, 1, acc11); EPIS(1, 2, acc12); EPIS(1, 3, acc13);
            EPIS(2, 0, acc20); EPIS(2, 1, acc21); EPIS(2, 2, acc22); EPIS(2, 3, acc23);
            EPIS(3, 0, acc30); EPIS(3, 1, acc31); EPIS(3, 2, acc32); EPIS(3, 3, acc33);
#undef EPIS
        }
    } else {
#define EPI(mi, ni, ACC)                                                        \
    do {                                                                        \
        const int gmb = m0 + wr * 64 + mi * 16 + 4 * lg;                        \
        const int gn = n0 + wc * 64 + ni * 16 + lr;                             \
        const float bia = bias[gn];                                             \
        _Pragma("unroll")                                                       \
        for (int i = 0; i < 4; ++i) {                                           \
            float v = ACC[i] + bia;                                             \
            const int row = gmb + i;                                            \
            if (MODE == 1) {                                                    \
                const float ge = 0.5f * v * (1.0f + erff(v * 0.70710678118654752f)); \
                ((bf16*)Cout)[(size_t)row * N + gn] = (bf16)ge;                 \
            } else {                                                            \
                const size_t off = (size_t)row * N + gn;                        \
                ((float*)Cout)[off] = v + add1[off] + add2[off];                \
            }                                                                   \
        }                                                                       \
    } while (0)
        EPI(0, 0, acc00); EPI(0, 1, acc01); EPI(0, 2, acc02); EPI(0, 3, acc03);
        EPI(1, 0, acc10); EPI(1, 1, acc11); EPI(1, 2, acc12); EPI(1, 3, acc13);
        EPI(2, 0, acc20); EPI(2, 1, acc21); EPI(2, 2, acc22); EPI(2, 3, acc23);
        EPI(3, 0, acc30); EPI(3, 1, acc31); EPI(3, 2, acc32); EPI(3, 3, acc33);
#undef EPI
    }
}

// ---------------------------------------------------------------- p_scalar finalize
__global__ __launch_bounds__(256) void pscalar_fin(const float* __restrict__ part,
                                                   float* __restrict__ ps) {
    const int i = blockIdx.x * 256 + threadIdx.x;   // 16384 rows
    float s = 0.f;
#pragma unroll
    for (int j = 0; j < 8; ++j) s += part[(size_t)j * MM + i];
    ps[i] = s * (1.f / 512.f);
}

// ---------------------------------------------------------------- scan
// 13-stage pipeline DP. Input: lint4[M][512][4] bf16 = {om, theta, re, im}
// (transform's sigmoid fused into GEMM0 epilogue). One 8B load per step.
#define SCL 32
__global__ __launch_bounds__(256) void scan_kernel(const bf16* __restrict__ lint4,
                                                   float* __restrict__ h_re) {
    const int blk = blockIdx.x;
    const int dh = blk & 1;
    const int tc = (blk >> 1) & 127;
    const int b = blk >> 8;
    const int d = dh * 256 + threadIdx.x;
    const int t0 = tc * SCL;

    float par[13], pai[13], pbr[13], pbi[13];
#pragma unroll
    for (int k = 0; k < 13; ++k) { par[k] = 0.f; pai[k] = 0.f; pbr[k] = 0.f; pbi[k] = 0.f; }

    const int warm = (tc == 0) ? 0 : 13;
    const bf16* tp = lint4 + ((size_t)(b * TT + t0 - warm) * 512 + d) * 4;
    float* pout = h_re + ((size_t)(b * TT + t0)) * DD + d;

#define XFORM(car, cai, cbr, cbi)                                        \
    const bf16x4 q_ = *(const bf16x4*)tp;                                \
    tp += 2048;                                                          \
    const float om = (float)q_[0];                                       \
    const float th = (float)q_[1];                                       \
    const float cbr = (float)q_[2];                                      \
    const float cbi = (float)q_[3];                                      \
    float fr_, sn, cs;                                                   \
    { const float rv_ = th * 0.15915494309189535f;                       \
      asm("v_fract_f32 %0, %1" : "=v"(fr_) : "v"(rv_));                  \
      asm("v_sin_f32 %0, %1" : "=v"(sn) : "v"(fr_));                     \
      asm("v_cos_f32 %0, %1" : "=v"(cs) : "v"(fr_)); }                   \
    float car = om * cs, cai = om * sn;

    for (int s = 0; s < warm; ++s) {
        XFORM(car, cai, cbr, cbi)
        float br_ = cbr, bi_ = cbi;
#pragma unroll
        for (int k = 0; k < 13; ++k) {
            const float tar = par[k], tai = pai[k], tbr = pbr[k], tbi = pbi[k];
            par[k] = car; pai[k] = cai; pbr[k] = br_; pbi[k] = bi_;
            const float nbr = car * tbr - cai * tbi + br_;
            const float nbi = car * tbi + cai * tbr + bi_;
            if (k < 12) {
                const float nar = car * tar - cai * tai;
                const float nai = car * tai + cai * tar;
                car = nar; cai = nai;
            }
            br_ = nbr; bi_ = nbi;
        }
    }

#pragma unroll 4
    for (int s = 0; s < SCL; ++s) {
        const int t = t0 + s;
        XFORM(car, cai, cbr, cbi)
        float br_ = cbr, bi_ = cbi;
        if (t == 0) {
#pragma unroll
            for (int k = 0; k < 13; ++k) { par[k] = car; pai[k] = cai; pbr[k] = br_; pbi[k] = bi_; }
        } else {
#pragma unroll
            for (int k = 0; k < 13; ++k) {
                const float tar = par[k], tai = pai[k], tbr = pbr[k], tbi = pbi[k];
                par[k] = car; pai[k] = cai; pbr[k] = br_; pbi[k] = bi_;
                const float nbr = car * tbr - cai * tbi + br_;
                const float nbi = car * tbi + cai * tbr + bi_;
                if (k < 12) {
                    const float nar = car * tar - cai * tai;
                    const float nai = car * tai + cai * tar;
                    car = nar; cai = nai;
                }
                br_ = nbr; bi_ = nbi;
            }
        }
        pout[(size_t)s * DD] = br_;
    }
#undef XFORM
}

// ---------------------------------------------------------------- h_mean partials
__global__ __launch_bounds__(256) void hmean_kernel(const float* __restrict__ h_re,
                                                    float* __restrict__ hsum) {
    const int blk = blockIdx.x;
    const int b = blk >> 6;
    const int dh = (blk >> 5) & 1;
    const int tc = blk & 31;
    const int d = dh * 256 + threadIdx.x;
    float s = 0.f;
    const float* p = h_re + ((size_t)(b * TT + tc * 128)) * DD + d;
    for (int t = 0; t < 128; ++t) s += p[(size_t)t * DD];
    atomicAdd(&hsum[b * DD + d], s);
}

// ---------------------------------------------------------------- top-16
__global__ __launch_bounds__(256) void topk_kernel(const float* __restrict__ ps,
                                                   int* __restrict__ idx_out) {
    __shared__ float vals[TT];
    __shared__ float rv[4];
    __shared__ int ri[4];
    const int b = blockIdx.x, tid = threadIdx.x;
    for (int i = tid; i < TT; i += 256) vals[i] = ps[b * TT + i];
    __syncthreads();
    for (int kk = 0; kk < 16; ++kk) {
        float bv = -1e30f; int bi = 0x7fffffff;
        for (int i = tid; i < TT; i += 256) {
            const float v = vals[i];
            if (v > bv || (v == bv && i < bi)) { bv = v; bi = i; }
        }
#pragma unroll
        for (int o = 32; o; o >>= 1) {
            const float ov = __shfl_down(bv, o);
            const int oi = __shfl_down(bi, o);
            if (ov > bv || (ov == bv && oi < bi)) { bv = ov; bi = oi; }
        }
        const int lane = tid & 63, wid = tid >> 6;
        if (!lane) { rv[wid] = bv; ri[wid] = bi; }
        __syncthreads();
        if (!tid) {
            float fbv = rv[0]; int fbi = ri[0];
            for (int w = 1; w < 4; ++w)
                if (rv[w] > fbv || (rv[w] == fbv && ri[w] < fbi)) { fbv = rv[w]; fbi = ri[w]; }
            idx_out[b * 16 + kk] = fbi;
            vals[fbi] = -1e30f;
        }
        __syncthreads();
    }
}

// ---------------------------------------------------------------- keys/values
__global__ __launch_bounds__(256) void kv_kernel(
    const float* __restrict__ h_re, const int* __restrict__ tki,
    const float* __restrict__ Wk, const float* __restrict__ Wkb,
    const float* __restrict__ Wv, const float* __restrict__ Wvb,
    float* __restrict__ keys, float* __restrict__ vals) {
    const int blk = blockIdx.x;
    const int b = blk >> 4, j = blk & 15;
    const int tid = threadIdx.x;
    __shared__ float hrow[512];
    const int row = tki[b * 16 + j];
    for (int i = tid; i < 512; i += 256)
        hrow[i] = h_re[((size_t)(b * TT + row)) * DD + i];
    __syncthreads();
    for (int n = tid; n < 512; n += 256) {
        float sk = Wkb[n], sv = Wvb[n];
        for (int k = 0; k < 512; ++k) {
            const float h = hrow[k];
            sk += h * Wk[(size_t)k * 512 + n];
            sv += h * Wv[(size_t)k * 512 + n];
        }
        keys[((size_t)(b * 16 + j)) * 512 + n] = sk;
        vals[((size_t)(b * 16 + j)) * 512 + n] = sv;
    }
}

// ---------------------------------------------------------------- query/gate/attn/out
__global__ __launch_bounds__(256) void attn_out_kernel(
    const float* __restrict__ hsum, const float* __restrict__ Wq,
    const float* __restrict__ Wqb, const float* __restrict__ gw,
    const float* __restrict__ gb, const float* __restrict__ keys,
    const float* __restrict__ vals, float* __restrict__ out1) {
    const int b = blockIdx.x, tid = threadIdx.x;
    const int lane = tid & 63, wid = tid >> 6;
    __shared__ float hm[512];
    __shared__ float q[512];
    __shared__ float sc[16];
    __shared__ float red[4];
    for (int d0 = tid; d0 < 512; d0 += 256)
        hm[d0] = hsum[b * 512 + d0] * (1.f / 4096.f);
    __syncthreads();
    for (int n = tid; n < 512; n += 256) {
        float s = Wqb[n];
        for (int k = 0; k < 512; ++k) s += hm[k] * Wq[(size_t)k * 512 + n];
        q[n] = s;
    }
    float gp = 0.f;
    for (int k = tid; k < 512; k += 256) gp += hm[k] * gw[k];
#pragma unroll
    for (int o = 32; o; o >>= 1) gp += __shfl_down(gp, o);
    if (!lane) red[wid] = gp;
    __syncthreads();
    const float g = 1.f / (1.f + __expf(-(red[0] + red[1] + red[2] + red[3] + gb[0])));
    for (int kk = wid; kk < 16; kk += 4) {
        float sp = 0.f;
        const float* kr = keys + ((size_t)(b * 16 + kk)) * 512;
        for (int k2 = lane; k2 < 512; k2 += 64) sp += q[k2] * kr[k2];
#pragma unroll
        for (int o = 32; o; o >>= 1) sp += __shfl_down(sp, o);
        if (!lane) sc[kk] = sp * 0.04419417382415922f;
    }
    __syncthreads();
    float mx = sc[0];
#pragma unroll
    for (int kk = 1; kk < 16; ++kk) mx = fmaxf(mx, sc[kk]);
    float den = 0.f;
    float w16[16];
#pragma unroll
    for (int kk = 0; kk < 16; ++kk) { w16[kk] = __expf(sc[kk] - mx); den += w16[kk]; }
    const float rden = 1.f / den;
    for (int d0 = tid; d0 < 512; d0 += 256) {
        float co = 0.f;
#pragma unroll
        for (int kk = 0; kk < 16; ++kk)
            co += w16[kk] * vals[((size_t)(b * 16 + kk)) * 512 + d0];
        out1[b * 512 + d0] = hm[d0] + g * (co * rden);
    }
}

// ---------------------------------------------------------------- launch
extern "C" void kernel_launch(void* const* d_in, const int* in_sizes, int n_in,
                              void* d_out, int out_size, void* d_ws, size_t ws_size,
                              hipStream_t stream) {
    const float* x    = (const float*)d_in[0];
    const float* ln1g = (const float*)d_in[1];
    const float* ln1b = (const float*)d_in[2];
    const float* ln2g = (const float*)d_in[3];
    const float* ln2b = (const float*)d_in[4];
    const float* Wp_w = (const float*)d_in[5];
    const float* Wp_b = (const float*)d_in[6];
    const float* Wt_w = (const float*)d_in[7];
    const float* Wt_b = (const float*)d_in[8];
    const float* Wr_w = (const float*)d_in[9];
    const float* Wr_b = (const float*)d_in[10];
    const float* Wi_w = (const float*)d_in[11];
    const float* Wi_b = (const float*)d_in[12];
    const float* Wk_w = (const float*)d_in[13];
    const float* Wk_b = (const float*)d_in[14];
    const float* Wv_w = (const float*)d_in[15];
    const float* Wv_b = (const float*)d_in[16];
    const float* Wq_w = (const float*)d_in[17];
    const float* Wq_b = (const float*)d_in[18];
    const float* gw   = (const float*)d_in[19];
    const float* gb   = (const float*)d_in[20];
    const float* f1w  = (const float*)d_in[21];
    const float* f1b  = (const float*)d_in[22];
    const float* f2w  = (const float*)d_in[23];
    const float* f2b  = (const float*)d_in[24];

    char* wsp = (char*)d_ws;
    bf16* lint4 = (bf16*)wsp;                        // [M][512][4] bf16 (67MB)
    char* p = wsp + 67108864;
    float* h_re = (float*)p; p += 33554432;          // [M][512] f32
    bf16* xn = (bf16*)p;     p += 16777216;          // [M][512] bf16
    bf16* hn = (bf16*)p;     p += 16777216;          // [M][512] bf16
    bf16* wcat = (bf16*)p;   p += 2097152;           // [2048][512] bf16 (Bt)
    bf16* f1bt = (bf16*)p;   p += 2097152;           // [2048][512] bf16
    bf16* f2bt = (bf16*)p;   p += 2097152;           // [512][2048] bf16
    float* bcat = (float*)p; p += 8192;              // [2048]
    float* ps = (float*)p;   p += 65536;             // [B][T]
    float* pspart = (float*)p; p += 524288;          // [8][M]
    float* hsum = (float*)p; p += 8192;              // [B][512]
    int* tki = (int*)p;      p += 256;               // [B][16]
    float* keys = (float*)p; p += 131072;            // [B][16][512]
    float* valsb = (float*)p;                        // [B][16][512]
    bf16* act = (bf16*)wsp;                          // [M][2048] bf16 overlays lint4
    float* out0 = (float*)d_out;
    float* out1 = (float*)d_out + OUT1_OFF;

    dim3 tb(32, 8);
    transpose_bf16<<<dim3(16, 16), tb, 0, stream>>>(Wp_w, wcat + (size_t)0 * 512 * 512, 512, 512);
    transpose_bf16<<<dim3(16, 16), tb, 0, stream>>>(Wt_w, wcat + (size_t)1 * 512 * 512, 512, 512);
    transpose_bf16<<<dim3(16, 16), tb, 0, stream>>>(Wr_w, wcat + (size_t)2 * 512 * 512, 512, 512);
    transpose_bf16<<<dim3(16, 16), tb, 0, stream>>>(Wi_w, wcat + (size_t)3 * 512 * 512, 512, 512);
    transpose_bf16<<<dim3(64, 16), tb, 0, stream>>>(f1w, f1bt, 512, 2048);
    transpose_bf16<<<dim3(16, 64), tb, 0, stream>>>(f2w, f2bt, 2048, 512);
    pack_bias<<<8, 256, 0, stream>>>(Wp_b, Wt_b, Wr_b, Wi_b, bcat);

    // LN1 -> xn
    ln_kernel<<<4096, 256, 0, stream>>>(x, nullptr, ln1g, ln1b, xn);
    // fused 4-projection GEMM + transform epilogue -> lint4 {om,th,re,im}; pscalar partials
    gemm_bt<0><<<2048, 256, 0, stream>>>(xn, wcat, bcat, lint4, pspart, nullptr, nullptr, MM, 2048, 512);
    // p_scalar finalize
    pscalar_fin<<<64, 256, 0, stream>>>(pspart, ps);
    // 13-stage pipeline scan -> h_re
    scan_kernel<<<1024, 256, 0, stream>>>(lint4, h_re);
    // h_mean partial sums
    zero_kernel<<<8, 256, 0, stream>>>(hsum, 2048);
    hmean_kernel<<<256, 256, 0, stream>>>(h_re, hsum);
    // cache path
    topk_kernel<<<4, 256, 0, stream>>>(ps, tki);
    kv_kernel<<<64, 256, 0, stream>>>(h_re, tki, Wk_w, Wk_b, Wv_w, Wv_b, keys, valsb);
    attn_out_kernel<<<4, 256, 0, stream>>>(hsum, Wq_w, Wq_b, gw, gb, keys, valsb, out1);
    // FFN path (act overlays lint4 -- safe: scan already consumed it)
    ln_kernel<<<4096, 256, 0, stream>>>(h_re, x, ln2g, ln2b, hn);
    gemm_bt<1><<<2048, 256, 0, stream>>>(hn, f1bt, f1b, act, nullptr, nullptr, nullptr, MM, 2048, 512);
    gemm_bt<2><<<512, 256, 0, stream>>>(act, f2bt, f2b, out0, nullptr, h_re, x, MM, 512, 2048);
}

// Round 12
// 409.587 us; speedup vs baseline: 1.2075x; 1.0243x over previous
//
#include <hip/hip_runtime.h>
#include <hip/hip_bf16.h>
#include <cstdint>
#include <cstddef>

typedef __bf16 bf16;
typedef __attribute__((ext_vector_type(8))) __bf16 bf16x8;
typedef __attribute__((ext_vector_type(4))) __bf16 bf16x4;
typedef __attribute__((ext_vector_type(4))) float f32x4;

#define BB 4
#define TT 4096
#define DD 512
#define MM (BB * TT)              // 16384 rows
#define OUT1_OFF ((size_t)MM * DD)

typedef __attribute__((address_space(1))) void as1_void;
typedef __attribute__((address_space(3))) void as3_void;

__device__ __forceinline__ void gl_lds16(const void* g, void* l) {
    __builtin_amdgcn_global_load_lds((as1_void*)(uintptr_t)g,
                                     (as3_void*)(uintptr_t)l, 16, 0, 0);
}

#define SIGM(x) (__builtin_amdgcn_rcpf(1.f + __expf(-(x))))

// ---------------------------------------------------------------- transpose
__global__ void transpose_bf16(const float* __restrict__ in, bf16* __restrict__ out,
                               int R, int C) {
    __shared__ float tile[32][33];
    const int c0 = blockIdx.x * 32, r0 = blockIdx.y * 32;
    const int tx = threadIdx.x, ty = threadIdx.y;
#pragma unroll
    for (int i = 0; i < 32; i += 8)
        tile[ty + i][tx] = in[(size_t)(r0 + ty + i) * C + (c0 + tx)];
    __syncthreads();
#pragma unroll
    for (int i = 0; i < 32; i += 8)
        out[(size_t)(c0 + ty + i) * R + (r0 + tx)] = (bf16)tile[tx][ty + i];
}

__global__ void pack_bias(const float* __restrict__ a, const float* __restrict__ b,
                          const float* __restrict__ c, const float* __restrict__ d,
                          float* __restrict__ o) {
    const int i = blockIdx.x * 256 + threadIdx.x;
    if (i < 2048) {
        const float* s = (i < 512) ? a : (i < 1024) ? b : (i < 1536) ? c : d;
        o[i] = s[i & 511];
    }
}

__global__ void zero_kernel(float* __restrict__ p, int n) {
    const int i = blockIdx.x * 256 + threadIdx.x;
    if (i < n) p[i] = 0.f;
}

// ---------------------------------------------------------------- layernorm
__global__ __launch_bounds__(256) void ln_kernel(
    const float* __restrict__ X, const float* __restrict__ Xadd,
    const float* __restrict__ gw, const float* __restrict__ bw,
    bf16* __restrict__ out) {
    const int row = blockIdx.x * 4 + (threadIdx.x >> 6);
    const int lane = threadIdx.x & 63;
    const float* xr = X + (size_t)row * DD + lane * 8;
    float v[8];
    float4 v0 = *(const float4*)xr;
    float4 v1 = *(const float4*)(xr + 4);
    v[0] = v0.x; v[1] = v0.y; v[2] = v0.z; v[3] = v0.w;
    v[4] = v1.x; v[5] = v1.y; v[6] = v1.z; v[7] = v1.w;
    if (Xadd) {
        const float* ad = Xadd + (size_t)row * DD + lane * 8;
        float4 a0 = *(const float4*)ad;
        float4 a1 = *(const float4*)(ad + 4);
        v[0] += a0.x; v[1] += a0.y; v[2] += a0.z; v[3] += a0.w;
        v[4] += a1.x; v[5] += a1.y; v[6] += a1.z; v[7] += a1.w;
    }
    float s = 0.f, ss = 0.f;
#pragma unroll
    for (int i = 0; i < 8; ++i) { s += v[i]; ss += v[i] * v[i]; }
#pragma unroll
    for (int o = 32; o; o >>= 1) { s += __shfl_down(s, o); ss += __shfl_down(ss, o); }
    s = __shfl(s, 0); ss = __shfl(ss, 0);
    const float mu = s * (1.f / DD);
    const float var = ss * (1.f / DD) - mu * mu;
    const float rstd = rsqrtf(var + 1e-5f);
    bf16x8 o8;
#pragma unroll
    for (int i = 0; i < 8; ++i)
        o8[i] = (bf16)((v[i] - mu) * rstd * gw[lane * 8 + i] + bw[lane * 8 + i]);
    *(bf16x8*)(out + (size_t)row * DD + lane * 8) = o8;
}

#define MF(a_, b_, c_) c_ = __builtin_amdgcn_mfma_f32_16x16x32_bf16(a_, b_, c_, 0, 0, 0)

// ---------------------------------------------------------------- GEMM (bf16 MFMA)
// 128x128/4-wave/BK=32, counted-vmcnt, T2 XOR swizzle (R10-proven), now
// TRI-BUFFERED with ONE barrier per K-step:
//   iter t: vmcnt(4) ; s_barrier ; ds_read buf[t%3] ; STG(t+2 -> buf[(t+2)%3])
//           ; 16 MFMA.
// Safety: buf[(t+2)%3] == buf[(t-1)%3]; every wave's tile-(t-1) ds_reads
// completed before its tile-(t-1) MFMAs, which precede the iter-t barrier
// => no read-after-overwrite hazard. The iter-t barrier + per-wave vmcnt(4)
// guarantees all waves' tile-t staging lines landed.
// MODE 0: fused transform epilogue (lint4 {om,th,re,im} + pscalar partials)
// MODE 1: bf16 out = gelu(acc + bias)
// MODE 2: f32 out = acc + bias + add1 + add2
template <int MODE>
__global__ __launch_bounds__(256) void gemm_bt(
    const bf16* __restrict__ A, const bf16* __restrict__ Bt,
    const float* __restrict__ bias, void* __restrict__ Cout,
    void* __restrict__ Cout2,
    const float* __restrict__ add1, const float* __restrict__ add2,
    int M, int N, int K) {
    __shared__ bf16 As[3][4096];
    __shared__ bf16 Bs[3][4096];
    const int tid = threadIdx.x;
    const int lane = tid & 63;
    const int wv = tid >> 6;
    const int wr = wv >> 1, wc = wv & 1;
    const int nb = N >> 7;
    const int nwg = gridDim.x;
    int bx = blockIdx.x;
    if ((nwg & 7) == 0) bx = (bx & 7) * (nwg >> 3) + (bx >> 3);  // XCD swizzle
    const int bm = bx / nb, bn = bx % nb;
    const int m0 = bm << 7, n0 = bn << 7;

    const int srow = tid >> 2;                              // staging row (0..63)
    const int scol = (((tid & 3) ^ ((tid >> 3) & 3)) << 3); // pre-swizzled global col
    const bf16* Asrc = A + (size_t)(m0 + srow) * K + scol;
    const bf16* Bsrc = Bt + (size_t)(n0 + srow) * K + scol;
    const size_t rstep = (size_t)64 * K;

    const int lr = lane & 15, lg = lane >> 4;
    const int sel = ((lg ^ ((lr >> 1) & 3)) << 3);          // swizzled 16B slot
    const int aoff = (wr * 64 + lr) * 32 + sel;
    const int boff = (wc * 64 + lr) * 32 + sel;

#define STG(buf, k0)                                                \
    do {                                                            \
        gl_lds16(Asrc + (k0),         &As[buf][wv * 512]);          \
        gl_lds16(Asrc + (k0) + rstep, &As[buf][wv * 512 + 2048]);   \
        gl_lds16(Bsrc + (k0),         &Bs[buf][wv * 512]);          \
        gl_lds16(Bsrc + (k0) + rstep, &Bs[buf][wv * 512 + 2048]);   \
    } while (0)

    f32x4 acc00 = {}, acc01 = {}, acc02 = {}, acc03 = {};
    f32x4 acc10 = {}, acc11 = {}, acc12 = {}, acc13 = {};
    f32x4 acc20 = {}, acc21 = {}, acc22 = {}, acc23 = {};
    f32x4 acc30 = {}, acc31 = {}, acc32 = {}, acc33 = {};

    const int NT = K >> 5;
    STG(0, 0);
    STG(1, 32);
    int cur = 0;                 // buffer of tile t (t % 3)
    for (int t = 0; t < NT; ++t) {
        if (t + 1 < NT) asm volatile("s_waitcnt vmcnt(4)" ::: "memory");
        else            asm volatile("s_waitcnt vmcnt(0)" ::: "memory");
        __builtin_amdgcn_s_barrier();
        asm volatile("" ::: "memory");
        const bf16* Ab = As[cur];
        const bf16* Bb = Bs[cur];
        bf16x8 af0 = *(const bf16x8*)&Ab[aoff];
        bf16x8 af1 = *(const bf16x8*)&Ab[aoff + 512];
        bf16x8 af2 = *(const bf16x8*)&Ab[aoff + 1024];
        bf16x8 af3 = *(const bf16x8*)&Ab[aoff + 1536];
        bf16x8 bf0 = *(const bf16x8*)&Bb[boff];
        bf16x8 bf1 = *(const bf16x8*)&Bb[boff + 512];
        bf16x8 bf2 = *(const bf16x8*)&Bb[boff + 1024];
        bf16x8 bf3 = *(const bf16x8*)&Bb[boff + 1536];
        // stage tile t+2 into freed buffer (t-1)%3 == (t+2)%3
        if (t + 2 < NT) {
            const int stg = (cur == 0) ? 2 : cur - 1;
            STG(stg, (t + 2) << 5);
        }
        MF(af0, bf0, acc00); MF(af0, bf1, acc01); MF(af0, bf2, acc02); MF(af0, bf3, acc03);
        MF(af1, bf0, acc10); MF(af1, bf1, acc11); MF(af1, bf2, acc12); MF(af1, bf3, acc13);
        MF(af2, bf0, acc20); MF(af2, bf1, acc21); MF(af2, bf2, acc22); MF(af2, bf3, acc23);
        MF(af3, bf0, acc30); MF(af3, bf1, acc31); MF(af3, bf2, acc32); MF(af3, bf3, acc33);
        cur = (cur == 2) ? 0 : cur + 1;
    }
#undef STG

    if constexpr (MODE == 0) {
        const int cls = n0 >> 9;                 // 0=p 1=theta 2=re 3=im
        if (cls == 0) {
            const int pidx = (n0 + wc * 64) >> 6;    // 0..7
#define EPI0(mi, A0, A1, A2, A3)                                              \
    do {                                                                      \
        const int gmb = m0 + wr * 64 + mi * 16 + 4 * lg;                      \
        const int dbase = n0 + wc * 64 + lr;                                  \
        const float b0_ = bias[dbase], b1_ = bias[dbase + 16],                \
                    b2_ = bias[dbase + 32], b3_ = bias[dbase + 48];           \
        _Pragma("unroll")                                                     \
        for (int i = 0; i < 4; ++i) {                                         \
            const int row = gmb + i;                                          \
            const float p0 = SIGM(A0[i] + b0_);                               \
            const float p1 = SIGM(A1[i] + b1_);                               \
            const float p2 = SIGM(A2[i] + b2_);                               \
            const float p3 = SIGM(A3[i] + b3_);                               \
            bf16* ob = (bf16*)Cout + (size_t)row * 2048;                      \
            ob[(size_t)dbase * 4]        = (bf16)(1.f - p0);                  \
            ob[(size_t)(dbase + 16) * 4] = (bf16)(1.f - p1);                  \
            ob[(size_t)(dbase + 32) * 4] = (bf16)(1.f - p2);                  \
            ob[(size_t)(dbase + 48) * 4] = (bf16)(1.f - p3);                  \
            float s_ = p0 + p1 + p2 + p3;                                     \
            s_ += __shfl_xor(s_, 1); s_ += __shfl_xor(s_, 2);                 \
            s_ += __shfl_xor(s_, 4); s_ += __shfl_xor(s_, 8);                 \
            if (lr == 0) ((float*)Cout2)[(size_t)pidx * MM + row] = s_;       \
        }                                                                     \
    } while (0)
            EPI0(0, acc00, acc01, acc02, acc03);
            EPI0(1, acc10, acc11, acc12, acc13);
            EPI0(2, acc20, acc21, acc22, acc23);
            EPI0(3, acc30, acc31, acc32, acc33);
#undef EPI0
        } else {
#define EPIS(mi, ni, ACC)                                                     \
    do {                                                                      \
        const int gmb = m0 + wr * 64 + mi * 16 + 4 * lg;                      \
        const int gn = n0 + wc * 64 + ni * 16 + lr;                           \
        const int dn = gn & 511;                                              \
        const float bia = bias[gn];                                           \
        _Pragma("unroll")                                                     \
        for (int i = 0; i < 4; ++i)                                           \
            ((bf16*)Cout)[((size_t)(gmb + i) * 512 + dn) * 4 + cls] =         \
                (bf16)(ACC[i] + bia);                                         \
    } while (0)
            EPIS(0, 0, acc00); EPIS(0, 1, acc01); EPIS(0, 2, acc02); EPIS(0, 3, acc03);
            EPIS(1, 0, acc10); EPIS(1, 1, acc11); EPIS(1, 2, acc12); EPIS(1, 3, acc13);
            EPIS(2, 0, acc20); EPIS(2, 1, acc21); EPIS(2, 2, acc22); EPIS(2, 3, acc23);
            EPIS(3, 0, acc30); EPIS(3, 1, acc31); EPIS(3, 2, acc32); EPIS(3, 3, acc33);
#undef EPIS
        }
    } else {
#define EPI(mi, ni, ACC)                                                        \
    do {                                                                        \
        const int gmb = m0 + wr * 64 + mi * 16 + 4 * lg;                        \
        const int gn = n0 + wc * 64 + ni * 16 + lr;                             \
        const float bia = bias[gn];                                             \
        _Pragma("unroll")                                                       \
        for (int i = 0; i < 4; ++i) {                                           \
            float v = ACC[i] + bia;                                             \
            const int row = gmb + i;                                            \
            if (MODE == 1) {                                                    \
                const float ge = 0.5f * v * (1.0f + erff(v * 0.70710678118654752f)); \
                ((bf16*)Cout)[(size_t)row * N + gn] = (bf16)ge;                 \
            } else {                                                            \
                const size_t off = (size_t)row * N + gn;                        \
                ((float*)Cout)[off] = v + add1[off] + add2[off];                \
            }                                                                   \
        }                                                                       \
    } while (0)
        EPI(0, 0, acc00); EPI(0, 1, acc01); EPI(0, 2, acc02); EPI(0, 3, acc03);
        EPI(1, 0, acc10); EPI(1, 1, acc11); EPI(1, 2, acc12); EPI(1, 3, acc13);
        EPI(2, 0, acc20); EPI(2, 1, acc21); EPI(2, 2, acc22); EPI(2, 3, acc23);
        EPI(3, 0, acc30); EPI(3, 1, acc31); EPI(3, 2, acc32); EPI(3, 3, acc33);
#undef EPI
    }
}

// ---------------------------------------------------------------- p_scalar finalize
__global__ __launch_bounds__(256) void pscalar_fin(const float* __restrict__ part,
                                                   float* __restrict__ ps) {
    const int i = blockIdx.x * 256 + threadIdx.x;   // 16384 rows
    float s = 0.f;
#pragma unroll
    for (int j = 0; j < 8; ++j) s += part[(size_t)j * MM + i];
    ps[i] = s * (1.f / 512.f);
}

// ---------------------------------------------------------------- scan
// 13-stage pipeline DP. Input: lint4[M][512][4] bf16 = {om, theta, re, im}.
// h_mean partial fused: each thread sums its 32 outputs -> one atomicAdd.
#define SCL 32
__global__ __launch_bounds__(256) void scan_kernel(const bf16* __restrict__ lint4,
                                                   float* __restrict__ h_re,
                                                   float* __restrict__ hsum) {
    const int blk = blockIdx.x;
    const int dh = blk & 1;
    const int tc = (blk >> 1) & 127;
    const int b = blk >> 8;
    const int d = dh * 256 + threadIdx.x;
    const int t0 = tc * SCL;

    float par[13], pai[13], pbr[13], pbi[13];
#pragma unroll
    for (int k = 0; k < 13; ++k) { par[k] = 0.f; pai[k] = 0.f; pbr[k] = 0.f; pbi[k] = 0.f; }

    const int warm = (tc == 0) ? 0 : 13;
    const bf16* tp = lint4 + ((size_t)(b * TT + t0 - warm) * 512 + d) * 4;
    float* pout = h_re + ((size_t)(b * TT + t0)) * DD + d;

#define XFORM(car, cai, cbr, cbi)                                        \
    const bf16x4 q_ = *(const bf16x4*)tp;                                \
    tp += 2048;                                                          \
    const float om = (float)q_[0];                                       \
    const float th = (float)q_[1];                                       \
    const float cbr = (float)q_[2];                                      \
    const float cbi = (float)q_[3];                                      \
    float fr_, sn, cs;                                                   \
    { const float rv_ = th * 0.15915494309189535f;                       \
      asm("v_fract_f32 %0, %1" : "=v"(fr_) : "v"(rv_));                  \
      asm("v_sin_f32 %0, %1" : "=v"(sn) : "v"(fr_));                     \
      asm("v_cos_f32 %0, %1" : "=v"(cs) : "v"(fr_)); }                   \
    float car = om * cs, cai = om * sn;

    for (int s = 0; s < warm; ++s) {
        XFORM(car, cai, cbr, cbi)
        float br_ = cbr, bi_ = cbi;
#pragma unroll
        for (int k = 0; k < 13; ++k) {
            const float tar = par[k], tai = pai[k], tbr = pbr[k], tbi = pbi[k];
            par[k] = car; pai[k] = cai; pbr[k] = br_; pbi[k] = bi_;
            const float nbr = car * tbr - cai * tbi + br_;
            const float nbi = car * tbi + cai * tbr + bi_;
            if (k < 12) {
                const float nar = car * tar - cai * tai;
                const float nai = car * tai + cai * tar;
                car = nar; cai = nai;
            }
            br_ = nbr; bi_ = nbi;
        }
    }

    float hacc = 0.f;
#pragma unroll 4
    for (int s = 0; s < SCL; ++s) {
        const int t = t0 + s;
        XFORM(car, cai, cbr, cbi)
        float br_ = cbr, bi_ = cbi;
        if (t == 0) {
#pragma unroll
            for (int k = 0; k < 13; ++k) { par[k] = car; pai[k] = cai; pbr[k] = br_; pbi[k] = bi_; }
        } else {
#pragma unroll
            for (int k = 0; k < 13; ++k) {
                const float tar = par[k], tai = pai[k], tbr = pbr[k], tbi = pbi[k];
                par[k] = car; pai[k] = cai; pbr[k] = br_; pbi[k] = bi_;
                const float nbr = car * tbr - cai * tbi + br_;
                const float nbi = car * tbi + cai * tbr + bi_;
                if (k < 12) {
                    const float nar = car * tar - cai * tai;
                    const float nai = car * tai + cai * tar;
                    car = nar; cai = nai;
                }
                br_ = nbr; bi_ = nbi;
            }
        }
        pout[(size_t)s * DD] = br_;
        hacc += br_;
    }
#undef XFORM
    atomicAdd(&hsum[b * DD + d], hacc);
}

// ---------------------------------------------------------------- top-16
__global__ __launch_bounds__(256) void topk_kernel(const float* __restrict__ ps,
                                                   int* __restrict__ idx_out) {
    __shared__ float vals[TT];
    __shared__ float rv[4];
    __shared__ int ri[4];
    const int b = blockIdx.x, tid = threadIdx.x;
    for (int i = tid; i < TT; i += 256) vals[i] = ps[b * TT + i];
    __syncthreads();
    for (int kk = 0; kk < 16; ++kk) {
        float bv = -1e30f; int bi = 0x7fffffff;
        for (int i = tid; i < TT; i += 256) {
            const float v = vals[i];
            if (v > bv || (v == bv && i < bi)) { bv = v; bi = i; }
        }
#pragma unroll
        for (int o = 32; o; o >>= 1) {
            const float ov = __shfl_down(bv, o);
            const int oi = __shfl_down(bi, o);
            if (ov > bv || (ov == bv && oi < bi)) { bv = ov; bi = oi; }
        }
        const int lane = tid & 63, wid = tid >> 6;
        if (!lane) { rv[wid] = bv; ri[wid] = bi; }
        __syncthreads();
        if (!tid) {
            float fbv = rv[0]; int fbi = ri[0];
            for (int w = 1; w < 4; ++w)
                if (rv[w] > fbv || (rv[w] == fbv && ri[w] < fbi)) { fbv = rv[w]; fbi = ri[w]; }
            idx_out[b * 16 + kk] = fbi;
            vals[fbi] = -1e30f;
        }
        __syncthreads();
    }
}

// ---------------------------------------------------------------- keys/values
__global__ __launch_bounds__(256) void kv_kernel(
    const float* __restrict__ h_re, const int* __restrict__ tki,
    const float* __restrict__ Wk, const float* __restrict__ Wkb,
    const float* __restrict__ Wv, const float* __restrict__ Wvb,
    float* __restrict__ keys, float* __restrict__ vals) {
    const int blk = blockIdx.x;
    const int b = blk >> 4, j = blk & 15;
    const int tid = threadIdx.x;
    __shared__ float hrow[512];
    const int row = tki[b * 16 + j];
    for (int i = tid; i < 512; i += 256)
        hrow[i] = h_re[((size_t)(b * TT + row)) * DD + i];
    __syncthreads();
    for (int n = tid; n < 512; n += 256) {
        float sk = Wkb[n], sv = Wvb[n];
        for (int k = 0; k < 512; ++k) {
            const float h = hrow[k];
            sk += h * Wk[(size_t)k * 512 + n];
            sv += h * Wv[(size_t)k * 512 + n];
        }
        keys[((size_t)(b * 16 + j)) * 512 + n] = sk;
        vals[((size_t)(b * 16 + j)) * 512 + n] = sv;
    }
}

// ---------------------------------------------------------------- query/gate/attn/out
__global__ __launch_bounds__(256) void attn_out_kernel(
    const float* __restrict__ hsum, const float* __restrict__ Wq,
    const float* __restrict__ Wqb, const float* __restrict__ gw,
    const float* __restrict__ gb, const float* __restrict__ keys,
    const float* __restrict__ vals, float* __restrict__ out1) {
    const int b = blockIdx.x, tid = threadIdx.x;
    const int lane = tid & 63, wid = tid >> 6;
    __shared__ float hm[512];
    __shared__ float q[512];
    __shared__ float sc[16];
    __shared__ float red[4];
    for (int d0 = tid; d0 < 512; d0 += 256)
        hm[d0] = hsum[b * 512 + d0] * (1.f / 4096.f);
    __syncthreads();
    for (int n = tid; n < 512; n += 256) {
        float s = Wqb[n];
        for (int k = 0; k < 512; ++k) s += hm[k] * Wq[(size_t)k * 512 + n];
        q[n] = s;
    }
    float gp = 0.f;
    for (int k = tid; k < 512; k += 256) gp += hm[k] * gw[k];
#pragma unroll
    for (int o = 32; o; o >>= 1) gp += __shfl_down(gp, o);
    if (!lane) red[wid] = gp;
    __syncthreads();
    const float g = 1.f / (1.f + __expf(-(red[0] + red[1] + red[2] + red[3] + gb[0])));
    for (int kk = wid; kk < 16; kk += 4) {
        float sp = 0.f;
        const float* kr = keys + ((size_t)(b * 16 + kk)) * 512;
        for (int k2 = lane; k2 < 512; k2 += 64) sp += q[k2] * kr[k2];
#pragma unroll
        for (int o = 32; o; o >>= 1) sp += __shfl_down(sp, o);
        if (!lane) sc[kk] = sp * 0.04419417382415922f;
    }
    __syncthreads();
    float mx = sc[0];
#pragma unroll
    for (int kk = 1; kk < 16; ++kk) mx = fmaxf(mx, sc[kk]);
    float den = 0.f;
    float w16[16];
#pragma unroll
    for (int kk = 0; kk < 16; ++kk) { w16[kk] = __expf(sc[kk] - mx); den += w16[kk]; }
    const float rden = 1.f / den;
    for (int d0 = tid; d0 < 512; d0 += 256) {
        float co = 0.f;
#pragma unroll
        for (int kk = 0; kk < 16; ++kk)
            co += w16[kk] * vals[((size_t)(b * 16 + kk)) * 512 + d0];
        out1[b * 512 + d0] = hm[d0] + g * (co * rden);
    }
}

// ---------------------------------------------------------------- launch
extern "C" void kernel_launch(void* const* d_in, const int* in_sizes, int n_in,
                              void* d_out, int out_size, void* d_ws, size_t ws_size,
                              hipStream_t stream) {
    const float* x    = (const float*)d_in[0];
    const float* ln1g = (const float*)d_in[1];
    const float* ln1b = (const float*)d_in[2];
    const float* ln2g = (const float*)d_in[3];
    const float* ln2b = (const float*)d_in[4];
    const float* Wp_w = (const float*)d_in[5];
    const float* Wp_b = (const float*)d_in[6];
    const float* Wt_w = (const float*)d_in[7];
    const float* Wt_b = (const float*)d_in[8];
    const float* Wr_w = (const float*)d_in[9];
    const float* Wr_b = (const float*)d_in[10];
    const float* Wi_w = (const float*)d_in[11];
    const float* Wi_b = (const float*)d_in[12];
    const float* Wk_w = (const float*)d_in[13];
    const float* Wk_b = (const float*)d_in[14];
    const float* Wv_w = (const float*)d_in[15];
    const float* Wv_b = (const float*)d_in[16];
    const float* Wq_w = (const float*)d_in[17];
    const float* Wq_b = (const float*)d_in[18];
    const float* gw   = (const float*)d_in[19];
    const float* gb   = (const float*)d_in[20];
    const float* f1w  = (const float*)d_in[21];
    const float* f1b  = (const float*)d_in[22];
    const float* f2w  = (const float*)d_in[23];
    const float* f2b  = (const float*)d_in[24];

    char* wsp = (char*)d_ws;
    bf16* lint4 = (bf16*)wsp;                        // [M][512][4] bf16 (67MB)
    char* p = wsp + 67108864;
    float* h_re = (float*)p; p += 33554432;          // [M][512] f32
    bf16* xn = (bf16*)p;     p += 16777216;          // [M][512] bf16
    bf16* hn = (bf16*)p;     p += 16777216;          // [M][512] bf16
    bf16* wcat = (bf16*)p;   p += 2097152;           // [2048][512] bf16 (Bt)
    bf16* f1bt = (bf16*)p;   p += 2097152;           // [2048][512] bf16
    bf16* f2bt = (bf16*)p;   p += 2097152;           // [512][2048] bf16
    float* bcat = (float*)p; p += 8192;              // [2048]
    float* ps = (float*)p;   p += 65536;             // [B][T]
    float* pspart = (float*)p; p += 524288;          // [8][M]
    float* hsum = (float*)p; p += 8192;              // [B][512]
    int* tki = (int*)p;      p += 256;               // [B][16]
    float* keys = (float*)p; p += 131072;            // [B][16][512]
    float* valsb = (float*)p;                        // [B][16][512]
    bf16* act = (bf16*)wsp;                          // [M][2048] bf16 overlays lint4
    float* out0 = (float*)d_out;
    float* out1 = (float*)d_out + OUT1_OFF;

    dim3 tb(32, 8);
    transpose_bf16<<<dim3(16, 16), tb, 0, stream>>>(Wp_w, wcat + (size_t)0 * 512 * 512, 512, 512);
    transpose_bf16<<<dim3(16, 16), tb, 0, stream>>>(Wt_w, wcat + (size_t)1 * 512 * 512, 512, 512);
    transpose_bf16<<<dim3(16, 16), tb, 0, stream>>>(Wr_w, wcat + (size_t)2 * 512 * 512, 512, 512);
    transpose_bf16<<<dim3(16, 16), tb, 0, stream>>>(Wi_w, wcat + (size_t)3 * 512 * 512, 512, 512);
    transpose_bf16<<<dim3(64, 16), tb, 0, stream>>>(f1w, f1bt, 512, 2048);
    transpose_bf16<<<dim3(16, 64), tb, 0, stream>>>(f2w, f2bt, 2048, 512);
    pack_bias<<<8, 256, 0, stream>>>(Wp_b, Wt_b, Wr_b, Wi_b, bcat);

    // LN1 -> xn
    ln_kernel<<<4096, 256, 0, stream>>>(x, nullptr, ln1g, ln1b, xn);
    // fused 4-projection GEMM + transform epilogue -> lint4; pscalar partials
    gemm_bt<0><<<2048, 256, 0, stream>>>(xn, wcat, bcat, lint4, pspart, nullptr, nullptr, MM, 2048, 512);
    // p_scalar finalize
    pscalar_fin<<<64, 256, 0, stream>>>(pspart, ps);
    // zero hsum, then scan (h_mean fused via atomics)
    zero_kernel<<<8, 256, 0, stream>>>(hsum, 2048);
    scan_kernel<<<1024, 256, 0, stream>>>(lint4, h_re, hsum);
    // cache path
    topk_kernel<<<4, 256, 0, stream>>>(ps, tki);
    kv_kernel<<<64, 256, 0, stream>>>(h_re, tki, Wk_w, Wk_b, Wv_w, Wv_b, keys, valsb);
    attn_out_kernel<<<4, 256, 0, stream>>>(hsum, Wq_w, Wq_b, gw, gb, keys, valsb, out1);
    // FFN path (act overlays lint4 -- safe: scan already consumed it)
    ln_kernel<<<4096, 256, 0, stream>>>(h_re, x, ln2g, ln2b, hn);
    gemm_bt<1><<<2048, 256, 0, stream>>>(hn, f1bt, f1b, act, nullptr, nullptr, nullptr, MM, 2048, 512);
    gemm_bt<2><<<512, 256, 0, stream>>>(act, f2bt, f2b, out0, nullptr, h_re, x, MM, 512, 2048);
}